// Round 1
// 2445.084 us; speedup vs baseline: 1.4108x; 1.4108x over previous
//
#include <hip/hip_runtime.h>
#include <cstdint>
#include <cstddef>

#define BLK 256

typedef __bf16 bf16x8 __attribute__((ext_vector_type(8)));
typedef float  f32x4  __attribute__((ext_vector_type(4)));

// ---------------------------------------------------------------- reductions
__device__ __forceinline__ float block_reduce_sum(float v, float* sm) {
#pragma unroll
  for (int off = 32; off > 0; off >>= 1) v += __shfl_down(v, off, 64);
  const int lane = threadIdx.x & 63;
  const int wid  = threadIdx.x >> 6;
  if (lane == 0) sm[wid] = v;
  __syncthreads();
  v = sm[0] + sm[1] + sm[2] + sm[3];
  __syncthreads();
  return v;
}

// ------------------------------------------------------- global average pool
__global__ __launch_bounds__(BLK) void gap_x_k(const float* __restrict__ x,
                                               float* __restrict__ y) {
  __shared__ float sm[4];
  const float4* p4 = reinterpret_cast<const float4*>(x + (size_t)blockIdx.x * 3136);
  float s = 0.f;
  for (int i = threadIdx.x; i < 784; i += BLK) {
    float4 v = p4[i];
    s += (v.x + v.y) + (v.z + v.w);
  }
  s = block_reduce_sum(s, sm);
  if (threadIdx.x == 0) y[blockIdx.x] = s * (1.f / 3136.f);
}

// ------------------------------------------------------------ gumbel mask
__global__ void mask_k(const float* __restrict__ y, const float* __restrict__ gumbel,
                       const float* __restrict__ nav_w, const float* __restrict__ nbg,
                       const float* __restrict__ nbb, const float* __restrict__ gsw,
                       const float* __restrict__ gsb, float* __restrict__ maskv,
                       float* __restrict__ mask_out) {
  int b = threadIdx.x;
  float d0 = 0.f, d1 = 0.f;
  for (int c = 0; c < 64; ++c) {
    float yv = y[b * 64 + c];
    d0 += yv * nav_w[c];
    d1 += yv * nav_w[64 + c];
  }
  float g0 = fmaxf(d0 * nbg[0] + nbb[0], 0.f);
  float g1 = fmaxf(d1 * nbg[1] + nbb[1], 0.f);
  int vid = b >> 3, s = b & 7;
  float l0 = gsw[s * 4 + 0] * g0 + gsw[s * 4 + 1] * g1 + gsb[s * 2 + 0] + gumbel[(vid * 8 + s) * 2 + 0];
  float l1 = gsw[s * 4 + 2] * g0 + gsw[s * 4 + 3] * g1 + gsb[s * 2 + 1] + gumbel[(vid * 8 + s) * 2 + 1];
  float m = (l1 > l0) ? 1.f : 0.f;
  maskv[b] = m;
  mask_out[b] = m;
}

// ------------------------------------------------ avgpool 3x3 s2 p1
__global__ __launch_bounds__(BLK) void avgpool_k(const float* __restrict__ x,
                                                 float* __restrict__ out) {
  int idx = blockIdx.x * BLK + threadIdx.x;
  int p = idx % 784;
  int bc = idx / 784;
  int h = p / 28, w = p % 28;
  const float* xp = x + (size_t)bc * 3136;
  int h0 = 2 * h - 1, w0 = 2 * w - 1;
  float s = 0.f;
#pragma unroll
  for (int i = 0; i < 3; ++i) {
    int hh = h0 + i;
    if (hh < 0 || hh >= 56) continue;
#pragma unroll
    for (int j = 0; j < 3; ++j) {
      int ww = w0 + j;
      if (ww < 0 || ww >= 56) continue;
      s += xp[hh * 56 + ww];
    }
  }
  out[idx] = s * (1.f / 9.f);
}

// ---------------------------------------------- fp32->bf16 [ch][pix] -> [pix][ch]
template <int C>
__global__ __launch_bounds__(BLK) void txp_k(const float* __restrict__ src,
                                             __bf16* __restrict__ dst, int NP) {
  __shared__ float t[C * 65];
  const int b = blockIdx.y;
  const int p0 = blockIdx.x * 64;
  for (int i = threadIdx.x; i < C * 64; i += BLK) {
    int c = i >> 6, p = i & 63;
    float v = 0.f;
    if (p0 + p < NP) v = src[((size_t)b * C + c) * NP + p0 + p];
    t[c * 65 + p] = v;
  }
  __syncthreads();
  constexpr int CQ = C / 8;
  for (int i = threadIdx.x; i < 64 * CQ; i += BLK) {
    int cq = i % CQ, pix = i / CQ;
    if (p0 + pix < NP) {
      __bf16 o[8];
#pragma unroll
      for (int j = 0; j < 8; ++j) o[j] = (__bf16)t[(cq * 8 + j) * 65 + pix];
      *reinterpret_cast<uint4*>(dst + ((size_t)b * NP + p0 + pix) * C + cq * 8) =
          *reinterpret_cast<uint4*>(o);
    }
  }
}

// ------------------------- fp32 direct conv ba_w1 (stride2), outputs bf16 [pix][ch]
__global__ __launch_bounds__(BLK) void conv_ba1_k(
    const float* __restrict__ in, const float* __restrict__ wgt,
    const float* __restrict__ gamma, const float* __restrict__ beta,
    __bf16* __restrict__ outT) {
  const int b = blockIdx.z;
  const int oc0 = blockIdx.y * 8;
  const size_t inPlane = 3136;
  const float* __restrict__ wb = wgt + (size_t)oc0 * 64 * 9;
  const float* __restrict__ xb = in + (size_t)b * 64 * inPlane;
  float gr[8], br[8];
#pragma unroll
  for (int j = 0; j < 8; ++j) {
    gr[j] = gamma[oc0 + j];
    br[j] = beta[oc0 + j];
  }
  for (int p = (int)threadIdx.x; p < 784; p += BLK) {
    int h = p / 28, w = p - h * 28;
    int hi = h * 2 - 1, wi = w * 2 - 1;
    float acc[8];
#pragma unroll
    for (int j = 0; j < 8; ++j) acc[j] = 0.f;
    bool interior = (hi >= 0) && (wi >= 0) && (hi + 2 < 56) && (wi + 2 < 56);
    if (interior) {
      const float* xp = xb + (size_t)hi * 56 + wi;
      for (int c = 0; c < 64; ++c) {
        const float* xr = xp + c * inPlane;
        float x0 = xr[0], x1 = xr[1], x2 = xr[2];
        float x3 = xr[56], x4 = xr[57], x5 = xr[58];
        float x6 = xr[112], x7 = xr[113], x8 = xr[114];
        const float* wc = wb + c * 9;
#pragma unroll
        for (int j = 0; j < 8; ++j) {
          const float* wj = wc + (size_t)j * 64 * 9;
          acc[j] += x0 * wj[0] + x1 * wj[1] + x2 * wj[2]
                  + x3 * wj[3] + x4 * wj[4] + x5 * wj[5]
                  + x6 * wj[6] + x7 * wj[7] + x8 * wj[8];
        }
      }
    } else {
      for (int c = 0; c < 64; ++c) {
        const float* xr = xb + c * inPlane;
        const float* wc = wb + c * 9;
#pragma unroll
        for (int dh = 0; dh < 3; ++dh) {
          int hh = hi + dh;
          if (hh < 0 || hh >= 56) continue;
#pragma unroll
          for (int dw = 0; dw < 3; ++dw) {
            int ww = wi + dw;
            if (ww < 0 || ww >= 56) continue;
            float xv = xr[(size_t)hh * 56 + ww];
#pragma unroll
            for (int j = 0; j < 8; ++j) acc[j] += xv * wc[(size_t)j * 64 * 9 + dh * 3 + dw];
          }
        }
      }
    }
    __bf16 o[8];
#pragma unroll
    for (int j = 0; j < 8; ++j) o[j] = (__bf16)fmaxf(acc[j] * gr[j] + br[j], 0.f);
    *reinterpret_cast<uint4*>(outT + ((size_t)b * 784 + p) * 64 + oc0) =
        *reinterpret_cast<uint4*>(o);
  }
}

// ------------------------------------------------------- weight prepack (3x3)
__global__ void pack3_k(const float* __restrict__ w, __bf16* __restrict__ dst,
                        int CIN, int MT) {
  int total = (CIN / 32) * 9 * MT * 64;
  int idx = blockIdx.x * BLK + threadIdx.x;
  if (idx >= total) return;
  int lane = idx & 63;
  int g = idx >> 6;
  int mt = g % MT; g /= MT;
  int t = g % 9;  int q = g / 9;
  int oc = mt * 16 + (lane & 15);
  int quad = lane >> 4;
#pragma unroll
  for (int j = 0; j < 8; ++j) {
    int c = q * 32 + quad * 8 + j;
    dst[(size_t)idx * 8 + j] = (__bf16)w[((size_t)oc * CIN + c) * 9 + t];
  }
}

// 1x1 variant
__global__ void pack1_k(const float* __restrict__ w, __bf16* __restrict__ dst,
                        int CIN, int MT) {
  int total = (CIN / 32) * MT * 64;
  int idx = blockIdx.x * BLK + threadIdx.x;
  if (idx >= total) return;
  int lane = idx & 63;
  int g = idx >> 6;
  int mt = g % MT;
  int q = g / MT;
  int oc = mt * 16 + (lane & 15);
  int quad = lane >> 4;
#pragma unroll
  for (int j = 0; j < 8; ++j) {
    int c = q * 32 + quad * 8 + j;
    dst[(size_t)idx * 8 + j] = (__bf16)w[(size_t)oc * CIN + c];
  }
}

// ------------------------------------------------ staging: bf16 [pix][ch] -> regs -> LDS
// LDS tile: [pix][32ch] bf16, pixel stride 40 (pad 8).  One 16B slot = 8 channels.
template <int W_IMG, int ROWS>
struct Stage {
  static constexpr int COLS  = W_IMG + 2;
  static constexpr int NSLOT = ROWS * COLS * 4;
  static constexpr int NIT   = (NSLOT + BLK - 1) / BLK;
  uint4 R[NIT];

  __device__ __forceinline__ void load(const __bf16* __restrict__ inT, int CIN, int c0,
                                       int img, int h0) {
    constexpr int NPIX = W_IMG * W_IMG;
#pragma unroll
    for (int it = 0; it < NIT; ++it) {
      int s = threadIdx.x + it * BLK;
      uint4 v{0u, 0u, 0u, 0u};
      if (s < NSLOT) {
        int pix = s >> 2, q = s & 3;
        int r = pix / COLS, cc = pix - r * COLS;
        int gh = h0 - 1 + r, gw = cc - 1;
        if (gh >= 0 && gh < W_IMG && gw >= 0 && gw < W_IMG)
          v = *reinterpret_cast<const uint4*>(
              inT + ((size_t)img * NPIX + gh * W_IMG + gw) * CIN + c0 + q * 8);
      }
      R[it] = v;
    }
  }

  __device__ __forceinline__ void store(__bf16* lds) {
#pragma unroll
    for (int it = 0; it < NIT; ++it) {
      int s = threadIdx.x + it * BLK;
      if (s < NSLOT) {
        int pix = s >> 2, q = s & 3;
        *reinterpret_cast<uint4*>(lds + pix * 40 + q * 8) = R[it];
      }
    }
  }
};

// --------------------------------------------------------- MFMA 3x3 conv
// block: 128 linear pixels x (MTW*2*16) ocs.  4 waves in 2x2 (wm, wn).
// MODE 0: relu(bn)  MODE 1: bn+res  MODE 2: relu(bn+res)
// OUTBF 1: write bf16 [pix][COUT] (MODE 0 semantics) via LDS transpose
template <int W_IMG, int CIN, int MTW, int MODE, int OUTBF>
__global__ __launch_bounds__(BLK, 2) void conv3_bf(
    const __bf16* __restrict__ inT, const __bf16* __restrict__ wp,
    const float* __restrict__ gamma, const float* __restrict__ beta,
    const float* __restrict__ res, void* __restrict__ outv) {
  constexpr int ROWS = 128 / W_IMG + 4;
  constexpr int COLS = W_IMG + 2;
  constexpr int NPIX = W_IMG * W_IMG;
  constexpr int NCH  = CIN / 32;
  constexpr int MT_TOT = MTW * 2;
  constexpr int COUT = MT_TOT * 16;
  constexpr int TILE_E = ROWS * COLS * 40;
  constexpr int LDSE = (OUTBF && 128 * COUT > TILE_E) ? 128 * COUT : TILE_E;
  __shared__ __bf16 lds[LDSE];

  const int tid = threadIdx.x;
  const int lane = tid & 63, wv = tid >> 6;
  const int wm = wv >> 1, wn = wv & 1;
  const int quad = lane >> 4, li = lane & 15;
  const int img = blockIdx.y;
  const int P0 = blockIdx.x * 128;
  const int h0 = P0 / W_IMG;

  int basee[4]; int pstore[4]; bool pok[4];
#pragma unroll
  for (int nt = 0; nt < 4; ++nt) {
    int p = P0 + wn * 64 + nt * 16 + li;
    bool ok = p < NPIX;
    int p2 = ok ? p : (NPIX - 1);
    int h = p2 / W_IMG, w = p2 - h * W_IMG;
    basee[nt] = ((h - h0) * COLS + w) * 40 + quad * 8;
    pstore[nt] = p2; pok[nt] = ok;
  }

  f32x4 acc[MTW][4];
#pragma unroll
  for (int mt = 0; mt < MTW; ++mt)
#pragma unroll
    for (int nt = 0; nt < 4; ++nt) acc[mt][nt] = (f32x4){0.f, 0.f, 0.f, 0.f};

  const bf16x8* wp8 = reinterpret_cast<const bf16x8*>(wp);

  Stage<W_IMG, ROWS> st;
  st.load(inT, CIN, 0, img, h0);
  for (int q = 0; q < NCH; ++q) {
    __syncthreads();            // prior chunk fully consumed
    st.store(lds);              // vmcnt-wait + ds_write
    __syncthreads();
    if (q + 1 < NCH) st.load(inT, CIN, (q + 1) * 32, img, h0);  // async under MFMAs
#pragma unroll
    for (int t = 0; t < 9; ++t) {
      const int toff = ((t / 3) * COLS + (t % 3)) * 40;
      bf16x8 wf[MTW];
#pragma unroll
      for (int mt = 0; mt < MTW; ++mt)
        wf[mt] = wp8[(size_t)((q * 9 + t) * MT_TOT + wm * MTW + mt) * 64 + lane];
      bf16x8 xf[4];
#pragma unroll
      for (int nt = 0; nt < 4; ++nt)
        xf[nt] = *reinterpret_cast<const bf16x8*>(&lds[basee[nt] + toff]);
#pragma unroll
      for (int mt = 0; mt < MTW; ++mt)
#pragma unroll
        for (int nt = 0; nt < 4; ++nt)
          acc[mt][nt] = __builtin_amdgcn_mfma_f32_16x16x32_bf16(wf[mt], xf[nt], acc[mt][nt], 0, 0, 0);
    }
  }

  if constexpr (!OUTBF) {
    float* out = (float*)outv;
#pragma unroll
    for (int mt = 0; mt < MTW; ++mt) {
#pragma unroll
      for (int r = 0; r < 4; ++r) {
        int oc = wm * MTW * 16 + mt * 16 + quad * 4 + r;
        float g = gamma[oc], bb = beta[oc];
#pragma unroll
        for (int nt = 0; nt < 4; ++nt) {
          if (!pok[nt]) continue;
          size_t idx = ((size_t)img * COUT + oc) * NPIX + pstore[nt];
          float v = acc[mt][nt][r] * g + bb;
          if constexpr (MODE == 1 || MODE == 2) v += res[idx];
          if constexpr (MODE == 0 || MODE == 2) v = fmaxf(v, 0.f);
          out[idx] = v;
        }
      }
    }
  } else {
    // bf16 [pix][COUT] output via swizzled LDS transpose -> coalesced 16B stores
    __bf16* outT = (__bf16*)outv;
    __syncthreads();  // tile reads done; reuse LDS
#pragma unroll
    for (int mt = 0; mt < MTW; ++mt) {
      int ocb = wm * MTW * 16 + mt * 16 + quad * 4;
      float g0 = gamma[ocb + 0], b0 = beta[ocb + 0];
      float g1 = gamma[ocb + 1], b1 = beta[ocb + 1];
      float g2 = gamma[ocb + 2], b2 = beta[ocb + 2];
      float g3 = gamma[ocb + 3], b3 = beta[ocb + 3];
#pragma unroll
      for (int nt = 0; nt < 4; ++nt) {
        if (!pok[nt]) continue;
        int pl = wn * 64 + nt * 16 + li;   // local pixel 0..127
        __bf16 o[4];
        o[0] = (__bf16)fmaxf(acc[mt][nt][0] * g0 + b0, 0.f);
        o[1] = (__bf16)fmaxf(acc[mt][nt][1] * g1 + b1, 0.f);
        o[2] = (__bf16)fmaxf(acc[mt][nt][2] * g2 + b2, 0.f);
        o[3] = (__bf16)fmaxf(acc[mt][nt][3] * g3 + b3, 0.f);
        int byt = pl * (COUT * 2) + ocb * 2;
        byt ^= (pl & 7) << 4;              // bank swizzle (row stride 256B)
        *reinterpret_cast<uint2*>(reinterpret_cast<char*>(lds) + byt) =
            *reinterpret_cast<uint2*>(o);
      }
    }
    __syncthreads();
    constexpr int SLOTS_ROW = COUT / 8;         // 16 (COUT=128)
    constexpr int ROWS_PASS = BLK / SLOTS_ROW;  // 16
#pragma unroll
    for (int pass = 0; pass < 128 / ROWS_PASS; ++pass) {
      int pl = pass * ROWS_PASS + (tid / SLOTS_ROW);
      int ss = tid % SLOTS_ROW;
      if (P0 + pl < NPIX) {
        int byt = pl * (COUT * 2) + ss * 16;
        byt ^= (pl & 7) << 4;
        uint4 vv = *reinterpret_cast<const uint4*>(reinterpret_cast<const char*>(lds) + byt);
        *reinterpret_cast<uint4*>(outT + ((size_t)img * NPIX + P0 + pl) * COUT + ss * 8) = vv;
      }
    }
  }
}

// --------------------- fused x_big: bn(1x1(x)) + mask * bn(3x3(h_f)), MFMA
__global__ __launch_bounds__(BLK, 2) void conv_xbig_bf(
    const __bf16* __restrict__ hfT, const __bf16* __restrict__ xT,
    const __bf16* __restrict__ wp3, const __bf16* __restrict__ wp1,
    const float* __restrict__ g2v, const float* __restrict__ b2v,
    const float* __restrict__ gdv, const float* __restrict__ bdv,
    const float* __restrict__ maskv, float* __restrict__ out) {
  constexpr int W_IMG = 56, ROWS = 6, COLS = 58, NPIX = 3136;
  __shared__ __bf16 lds[ROWS * COLS * 40];

  const int tid = threadIdx.x;
  const int lane = tid & 63, wv = tid >> 6;
  const int wm = wv >> 1, wn = wv & 1;
  const int quad = lane >> 4, li = lane & 15;
  const int img = blockIdx.y;
  const int P0 = blockIdx.x * 128;
  const int h0 = P0 / W_IMG;
  const float m = maskv[img];

  int basee[4]; int pstore[4]; bool pok[4];
#pragma unroll
  for (int nt = 0; nt < 4; ++nt) {
    int p = P0 + wn * 64 + nt * 16 + li;
    bool ok = p < NPIX;
    int p2 = ok ? p : (NPIX - 1);
    int h = p2 / W_IMG, w = p2 - h * W_IMG;
    basee[nt] = ((h - h0) * COLS + w) * 40 + quad * 8;
    pstore[nt] = p2; pok[nt] = ok;
  }

  f32x4 acc3[4][4], acc1[4][4];
#pragma unroll
  for (int mt = 0; mt < 4; ++mt)
#pragma unroll
    for (int nt = 0; nt < 4; ++nt) {
      acc3[mt][nt] = (f32x4){0.f, 0.f, 0.f, 0.f};
      acc1[mt][nt] = (f32x4){0.f, 0.f, 0.f, 0.f};
    }

  const bf16x8* wp3v = reinterpret_cast<const bf16x8*>(wp3);
  const bf16x8* wp1v = reinterpret_cast<const bf16x8*>(wp1);

  Stage<56, 6> st;
  st.load(hfT, 128, 0, img, h0);

  // phase 1: 3x3 over h_f, CIN=128
  for (int q = 0; q < 4; ++q) {
    __syncthreads();
    st.store(lds);
    __syncthreads();
    if (q < 3) st.load(hfT, 128, (q + 1) * 32, img, h0);
    else       st.load(xT, 64, 0, img, h0);
#pragma unroll
    for (int t = 0; t < 9; ++t) {
      const int toff = ((t / 3) * COLS + (t % 3)) * 40;
      bf16x8 wf[4];
#pragma unroll
      for (int mt = 0; mt < 4; ++mt)
        wf[mt] = wp3v[(size_t)(((q * 9 + t) * 8) + wm * 4 + mt) * 64 + lane];
      bf16x8 xf[4];
#pragma unroll
      for (int nt = 0; nt < 4; ++nt)
        xf[nt] = *reinterpret_cast<const bf16x8*>(&lds[basee[nt] + toff]);
#pragma unroll
      for (int mt = 0; mt < 4; ++mt)
#pragma unroll
        for (int nt = 0; nt < 4; ++nt)
          acc3[mt][nt] = __builtin_amdgcn_mfma_f32_16x16x32_bf16(wf[mt], xf[nt], acc3[mt][nt], 0, 0, 0);
    }
  }

  // phase 2: 1x1 over x, CIN=64 (center tap)
  for (int q = 0; q < 2; ++q) {
    __syncthreads();
    st.store(lds);
    __syncthreads();
    if (q == 0) st.load(xT, 64, 32, img, h0);
    const int toff = (1 * COLS + 1) * 40;
    bf16x8 wf[4];
#pragma unroll
    for (int mt = 0; mt < 4; ++mt)
      wf[mt] = wp1v[(size_t)((q * 8) + wm * 4 + mt) * 64 + lane];
    bf16x8 xf[4];
#pragma unroll
    for (int nt = 0; nt < 4; ++nt)
      xf[nt] = *reinterpret_cast<const bf16x8*>(&lds[basee[nt] + toff]);
#pragma unroll
    for (int mt = 0; mt < 4; ++mt)
#pragma unroll
      for (int nt = 0; nt < 4; ++nt)
        acc1[mt][nt] = __builtin_amdgcn_mfma_f32_16x16x32_bf16(wf[mt], xf[nt], acc1[mt][nt], 0, 0, 0);
  }

#pragma unroll
  for (int mt = 0; mt < 4; ++mt) {
#pragma unroll
    for (int r = 0; r < 4; ++r) {
      int oc = wm * 64 + mt * 16 + quad * 4 + r;
      float g2 = g2v[oc], b2 = b2v[oc], gd = gdv[oc], bd = bdv[oc];
#pragma unroll
      for (int nt = 0; nt < 4; ++nt) {
        if (!pok[nt]) continue;
        size_t idx = ((size_t)img * 128 + oc) * NPIX + pstore[nt];
        float v = (acc1[mt][nt][r] * gd + bd) + m * (acc3[mt][nt][r] * g2 + b2);
        out[idx] = v;
      }
    }
  }
}

// --------------------------------------------- base_transform 1x1 conv + bn
__global__ __launch_bounds__(BLK) void conv1x1_bt_k(
    const float* __restrict__ xl, const float* __restrict__ w,
    const float* __restrict__ g, const float* __restrict__ bt, float* __restrict__ out) {
  const int b = blockIdx.z;
  const int oc0 = blockIdx.y * 8;
  const float* __restrict__ xp = xl + (size_t)b * 64 * 784;
  float gr[8], br[8];
#pragma unroll
  for (int j = 0; j < 8; ++j) {
    gr[j] = g[oc0 + j];
    br[j] = bt[oc0 + j];
  }
  for (int p = (int)threadIdx.x; p < 784; p += BLK) {
    float acc[8];
#pragma unroll
    for (int j = 0; j < 8; ++j) acc[j] = 0.f;
    for (int c = 0; c < 64; ++c) {
      float xv = xp[c * 784 + p];
#pragma unroll
      for (int j = 0; j < 8; ++j) acc[j] += xv * w[(oc0 + j) * 64 + c];
    }
#pragma unroll
    for (int j = 0; j < 8; ++j)
      out[(size_t)(b * 128 + oc0 + j) * 784 + p] = acc[j] * gr[j] + br[j];
  }
}

// ------------------------------------- GAP of (x_big + upsampled x_little)
__global__ __launch_bounds__(BLK) void gap2_k(const float* __restrict__ xbig,
                                              const float* __restrict__ xlbt,
                                              float* __restrict__ ysum) {
  __shared__ float sm1[4], sm2[4];
  const int bo = blockIdx.x;
  const float4* p4 = reinterpret_cast<const float4*>(xbig + (size_t)bo * 3136);
  float s1 = 0.f;
  for (int i = threadIdx.x; i < 784; i += BLK) {
    float4 v = p4[i];
    s1 += (v.x + v.y) + (v.z + v.w);
  }
  const float4* q4 = reinterpret_cast<const float4*>(xlbt + (size_t)bo * 784);
  float s2 = 0.f;
  for (int i = threadIdx.x; i < 196; i += BLK) {
    float4 v = q4[i];
    s2 += (v.x + v.y) + (v.z + v.w);
  }
  s1 = block_reduce_sum(s1, sm1);
  s2 = block_reduce_sum(s2, sm2);
  if (threadIdx.x == 0) ysum[bo] = s1 * (1.f / 3136.f) + s2 * (1.f / 784.f);
}

// ----------------------------------------------------- SE attention weights
__global__ void att_k(const float* __restrict__ ysum, const float* __restrict__ w1,
                      const float* __restrict__ w2, float* __restrict__ att) {
  int b = blockIdx.x;
  int t = threadIdx.x;
  __shared__ float hid[8];
  __shared__ float ybuf[128];
  ybuf[t] = ysum[b * 128 + t];
  __syncthreads();
  if (t < 8) {
    float s = 0.f;
    for (int c = 0; c < 128; ++c) s += ybuf[c] * w1[t * 128 + c];
    hid[t] = fmaxf(s, 0.f);
  }
  __syncthreads();
  float s = 0.f;
#pragma unroll
  for (int j = 0; j < 8; ++j) s += hid[j] * w2[t * 8 + j];
  att[b * 128 + t] = 1.f / (1.f + expf(-s));
}

// ------------------------------- SE combine: relu(a*xl_up + (1-a)*x_big)
__global__ __launch_bounds__(BLK) void se_k(const float* __restrict__ xlbt,
                                            const float* __restrict__ att,
                                            float* __restrict__ out) {
  int idx = blockIdx.x * BLK + threadIdx.x;
  int p = idx % 3136;
  int bo = idx / 3136;
  int h = p / 56, w = p % 56;
  float a = att[bo];
  float xl = xlbt[(size_t)bo * 784 + (h >> 1) * 28 + (w >> 1)];
  float xb = out[idx];
  out[idx] = fmaxf(a * xl + (1.f - a) * xb, 0.f);
}

// ---------------------------------------------------------------- launcher
extern "C" void kernel_launch(void* const* d_in, const int* in_sizes, int n_in,
                              void* d_out, int out_size, void* d_ws, size_t ws_size,
                              hipStream_t stream) {
  const float* x      = (const float*)d_in[0];
  const float* gumbel = (const float*)d_in[1];
  const float* nav_w  = (const float*)d_in[2];
  const float* nbg    = (const float*)d_in[3];
  const float* nbb    = (const float*)d_in[4];
  const float* gsw    = (const float*)d_in[5];
  const float* gsb    = (const float*)d_in[6];
  const float* ba_w1  = (const float*)d_in[7];
  const float* ba_g1  = (const float*)d_in[8];
  const float* ba_b1  = (const float*)d_in[9];
  const float* ba_w2  = (const float*)d_in[10];
  const float* ba_g2  = (const float*)d_in[11];
  const float* ba_b2  = (const float*)d_in[12];
  const float* bf_wd  = (const float*)d_in[13];
  const float* bf_gd  = (const float*)d_in[14];
  const float* bf_bd  = (const float*)d_in[15];
  const float* bf_w1  = (const float*)d_in[16];
  const float* bf_g1  = (const float*)d_in[17];
  const float* bf_b1  = (const float*)d_in[18];
  const float* bf_w2  = (const float*)d_in[19];
  const float* bf_g2  = (const float*)d_in[20];
  const float* bf_b2  = (const float*)d_in[21];
  const float* bt_w   = (const float*)d_in[22];
  const float* bt_g   = (const float*)d_in[23];
  const float* bt_b   = (const float*)d_in[24];
  const float* att_w1 = (const float*)d_in[25];
  const float* att_w2 = (const float*)d_in[26];
  const float* fu_w1  = (const float*)d_in[27];
  const float* fu_g1  = (const float*)d_in[28];
  const float* fu_b1  = (const float*)d_in[29];
  const float* fu_w2  = (const float*)d_in[30];
  const float* fu_g2  = (const float*)d_in[31];
  const float* fu_b2  = (const float*)d_in[32];

  float* out = (float*)d_out;
  float* ws  = (float*)d_ws;

  const size_t N_OUT = 51380224;  // 128*128*56*56
  float* bufA = ws;               // 51.38M-float region, re-purposed for bf16 buffers:
  //   A1 [0, 25690112): hfbf then hfubf  (51,380,224 bf16 = [img][3136][128])
  //   A2 [25690112, 51380224): xbf (25,690,112 bf16 = [img][3136][64]) then outbf
  __bf16* hfbf  = (__bf16*)bufA;
  __bf16* hfubf = (__bf16*)bufA;
  __bf16* xbf   = (__bf16*)(bufA + 25690112);
  __bf16* outbf = (__bf16*)(bufA + 25690112);
  float* xlbt = bufA + N_OUT;     // [128,128,28,28]
  float* resl = xlbt + 12845056;  // res_l -> x_little
  __bf16* habf = (__bf16*)(resl + 6422528);  // [128,784,64] bf16 (uses 3.21M floats of old ha slot)
  float* ygap = resl + 6422528 + 6422528;    // [128,64]
  float* mskv = ygap + 8192;      // [128]
  float* ysum = mskv + 128;       // [128,128]
  float* attb = ysum + 16384;     // [128,128]
  float* wend = attb + 16384;
  // bf16 weight packs (sizes in floats = bf16elems/2)
  __bf16* wsW1 = (__bf16*)(wend);                 // 73728 bf16
  __bf16* wsW2 = (__bf16*)(wend + 36864);         // 147456 bf16
  __bf16* wsF1 = (__bf16*)(wend + 110592);        // 147456 bf16
  __bf16* wsF2 = (__bf16*)(wend + 184320);        // 147456 bf16
  __bf16* wsA2 = (__bf16*)(wend + 258048);        // 36864 bf16
  __bf16* wsWd = (__bf16*)(wend + 276480);        // 8192 bf16
  float* mask_out = out + ((size_t)out_size - 128);

  // weight prepack (bf16 fragment layout)
  pack3_k<<<36, BLK, 0, stream>>>(bf_w1, wsW1, 64, 8);
  pack3_k<<<72, BLK, 0, stream>>>(bf_w2, wsW2, 128, 8);
  pack3_k<<<72, BLK, 0, stream>>>(fu_w1, wsF1, 128, 8);
  pack3_k<<<72, BLK, 0, stream>>>(fu_w2, wsF2, 128, 8);
  pack3_k<<<18, BLK, 0, stream>>>(ba_w2, wsA2, 64, 4);
  pack1_k<<<4, BLK, 0, stream>>>(bf_wd, wsWd, 64, 8);

  // x -> bf16 [pix][64]
  txp_k<64><<<dim3(49, 128), BLK, 0, stream>>>(x, xbf, 3136);

  // navigation mask
  gap_x_k<<<8192, BLK, 0, stream>>>(x, ygap);
  mask_k<<<1, 128, 0, stream>>>(ygap, gumbel, nav_w, nbg, nbb, gsw, gsb, mskv, mask_out);

  // ample branch
  avgpool_k<<<25088, BLK, 0, stream>>>(x, resl);
  conv_ba1_k<<<dim3(1, 8, 128), BLK, 0, stream>>>(x, ba_w1, ba_g1, ba_b1, habf);
  conv3_bf<28, 64, 2, 1, 0><<<dim3(7, 128), BLK, 0, stream>>>(
      habf, wsA2, ba_g2, ba_b2, resl, resl);
  conv1x1_bt_k<<<dim3(1, 16, 128), BLK, 0, stream>>>(resl, bt_w, bt_g, bt_b, xlbt);

  // focal branch
  conv3_bf<56, 64, 4, 0, 1><<<dim3(25, 128), BLK, 0, stream>>>(
      xbf, wsW1, bf_g1, bf_b1, nullptr, hfbf);
  conv_xbig_bf<<<dim3(25, 128), BLK, 0, stream>>>(
      hfbf, xbf, wsW2, wsWd, bf_g2, bf_b2, bf_gd, bf_bd, mskv, out);

  // SE fusion
  gap2_k<<<16384, BLK, 0, stream>>>(out, xlbt, ysum);
  att_k<<<128, 128, 0, stream>>>(ysum, att_w1, att_w2, attb);
  se_k<<<200704, BLK, 0, stream>>>(xlbt, attb, out);

  // out -> bf16 [pix][128]  (xbf is dead now; reuse A2)
  txp_k<128><<<dim3(49, 128), BLK, 0, stream>>>(out, outbf, 3136);

  // fusion residual block
  conv3_bf<56, 128, 4, 0, 1><<<dim3(25, 128), BLK, 0, stream>>>(
      outbf, wsF1, fu_g1, fu_b1, nullptr, hfubf);
  conv3_bf<56, 128, 4, 2, 0><<<dim3(25, 128), BLK, 0, stream>>>(
      hfubf, wsF2, fu_g2, fu_b2, out, out);
}

// Round 3
// 1968.663 us; speedup vs baseline: 1.7522x; 1.2420x over previous
//
#include <hip/hip_runtime.h>
#include <cstdint>
#include <cstddef>

#define BLK 256

typedef __bf16 bf16x8 __attribute__((ext_vector_type(8)));
typedef float  f32x4  __attribute__((ext_vector_type(4)));

// ---------------------------------------------------------------- reductions
__device__ __forceinline__ float block_reduce_sum(float v, float* sm) {
#pragma unroll
  for (int off = 32; off > 0; off >>= 1) v += __shfl_down(v, off, 64);
  const int lane = threadIdx.x & 63;
  const int wid  = threadIdx.x >> 6;
  if (lane == 0) sm[wid] = v;
  __syncthreads();
  v = sm[0] + sm[1] + sm[2] + sm[3];
  __syncthreads();
  return v;
}

// ------------------------------------------------------- global average pool
__global__ __launch_bounds__(BLK) void gap_x_k(const float* __restrict__ x,
                                               float* __restrict__ y) {
  __shared__ float sm[4];
  const float4* p4 = reinterpret_cast<const float4*>(x + (size_t)blockIdx.x * 3136);
  float s = 0.f;
  for (int i = threadIdx.x; i < 784; i += BLK) {
    float4 v = p4[i];
    s += (v.x + v.y) + (v.z + v.w);
  }
  s = block_reduce_sum(s, sm);
  if (threadIdx.x == 0) y[blockIdx.x] = s * (1.f / 3136.f);
}

// ------------------------------------------------------------ gumbel mask
__global__ void mask_k(const float* __restrict__ y, const float* __restrict__ gumbel,
                       const float* __restrict__ nav_w, const float* __restrict__ nbg,
                       const float* __restrict__ nbb, const float* __restrict__ gsw,
                       const float* __restrict__ gsb, float* __restrict__ maskv,
                       float* __restrict__ mask_out) {
  int b = threadIdx.x;
  float d0 = 0.f, d1 = 0.f;
  for (int c = 0; c < 64; ++c) {
    float yv = y[b * 64 + c];
    d0 += yv * nav_w[c];
    d1 += yv * nav_w[64 + c];
  }
  float g0 = fmaxf(d0 * nbg[0] + nbb[0], 0.f);
  float g1 = fmaxf(d1 * nbg[1] + nbb[1], 0.f);
  int vid = b >> 3, s = b & 7;
  float l0 = gsw[s * 4 + 0] * g0 + gsw[s * 4 + 1] * g1 + gsb[s * 2 + 0] + gumbel[(vid * 8 + s) * 2 + 0];
  float l1 = gsw[s * 4 + 2] * g0 + gsw[s * 4 + 3] * g1 + gsb[s * 2 + 1] + gumbel[(vid * 8 + s) * 2 + 1];
  float m = (l1 > l0) ? 1.f : 0.f;
  maskv[b] = m;
  mask_out[b] = m;
}

// ------------------------------------------------ avgpool 3x3 s2 p1
__global__ __launch_bounds__(BLK) void avgpool_k(const float* __restrict__ x,
                                                 float* __restrict__ out) {
  int idx = blockIdx.x * BLK + threadIdx.x;
  int p = idx % 784;
  int bc = idx / 784;
  int h = p / 28, w = p % 28;
  const float* xp = x + (size_t)bc * 3136;
  int h0 = 2 * h - 1, w0 = 2 * w - 1;
  float s = 0.f;
#pragma unroll
  for (int i = 0; i < 3; ++i) {
    int hh = h0 + i;
    if (hh < 0 || hh >= 56) continue;
#pragma unroll
    for (int j = 0; j < 3; ++j) {
      int ww = w0 + j;
      if (ww < 0 || ww >= 56) continue;
      s += xp[hh * 56 + ww];
    }
  }
  out[idx] = s * (1.f / 9.f);
}

// ---------------------------------------------- fp32->bf16 [ch][pix] -> [pix][ch]
template <int C>
__global__ __launch_bounds__(BLK) void txp_k(const float* __restrict__ src,
                                             __bf16* __restrict__ dst, int NP) {
  __shared__ float t[C * 65];
  const int b = blockIdx.y;
  const int p0 = blockIdx.x * 64;
  for (int i = threadIdx.x; i < C * 64; i += BLK) {
    int c = i >> 6, p = i & 63;
    float v = 0.f;
    if (p0 + p < NP) v = src[((size_t)b * C + c) * NP + p0 + p];
    t[c * 65 + p] = v;
  }
  __syncthreads();
  constexpr int CQ = C / 8;
  for (int i = threadIdx.x; i < 64 * CQ; i += BLK) {
    int cq = i % CQ, pix = i / CQ;
    if (p0 + pix < NP) {
      __bf16 o[8];
#pragma unroll
      for (int j = 0; j < 8; ++j) o[j] = (__bf16)t[(cq * 8 + j) * 65 + pix];
      *reinterpret_cast<uint4*>(dst + ((size_t)b * NP + p0 + pix) * C + cq * 8) =
          *reinterpret_cast<uint4*>(o);
    }
  }
}

// ------------------------------------------------------- weight prepack (3x3)
__global__ void pack3_k(const float* __restrict__ w, __bf16* __restrict__ dst,
                        int CIN, int MT) {
  int total = (CIN / 32) * 9 * MT * 64;
  int idx = blockIdx.x * BLK + threadIdx.x;
  if (idx >= total) return;
  int lane = idx & 63;
  int g = idx >> 6;
  int mt = g % MT; g /= MT;
  int t = g % 9;  int q = g / 9;
  int oc = mt * 16 + (lane & 15);
  int quad = lane >> 4;
#pragma unroll
  for (int j = 0; j < 8; ++j) {
    int c = q * 32 + quad * 8 + j;
    dst[(size_t)idx * 8 + j] = (__bf16)w[((size_t)oc * CIN + c) * 9 + t];
  }
}

// 1x1 variant
__global__ void pack1_k(const float* __restrict__ w, __bf16* __restrict__ dst,
                        int CIN, int MT) {
  int total = (CIN / 32) * MT * 64;
  int idx = blockIdx.x * BLK + threadIdx.x;
  if (idx >= total) return;
  int lane = idx & 63;
  int g = idx >> 6;
  int mt = g % MT;
  int q = g / MT;
  int oc = mt * 16 + (lane & 15);
  int quad = lane >> 4;
#pragma unroll
  for (int j = 0; j < 8; ++j) {
    int c = q * 32 + quad * 8 + j;
    dst[(size_t)idx * 8 + j] = (__bf16)w[(size_t)oc * CIN + c];
  }
}

// ------------------------------------------------ staging: bf16 [pix][ch] -> regs -> LDS
// LDS tile: [pix][32ch] bf16, pixel stride 40 (pad 8).  One 16B slot = 8 channels.
template <int W_IMG, int ROWS>
struct Stage {
  static constexpr int COLS  = W_IMG + 2;
  static constexpr int NSLOT = ROWS * COLS * 4;
  static constexpr int NIT   = (NSLOT + BLK - 1) / BLK;
  uint4 R[NIT];

  __device__ __forceinline__ void load(const __bf16* __restrict__ inT, int CIN, int c0,
                                       int img, int h0) {
    constexpr int NPIX = W_IMG * W_IMG;
#pragma unroll
    for (int it = 0; it < NIT; ++it) {
      int s = threadIdx.x + it * BLK;
      uint4 v{0u, 0u, 0u, 0u};
      if (s < NSLOT) {
        int pix = s >> 2, q = s & 3;
        int r = pix / COLS, cc = pix - r * COLS;
        int gh = h0 - 1 + r, gw = cc - 1;
        if (gh >= 0 && gh < W_IMG && gw >= 0 && gw < W_IMG)
          v = *reinterpret_cast<const uint4*>(
              inT + ((size_t)img * NPIX + gh * W_IMG + gw) * CIN + c0 + q * 8);
      }
      R[it] = v;
    }
  }

  __device__ __forceinline__ void store(__bf16* lds) {
#pragma unroll
    for (int it = 0; it < NIT; ++it) {
      int s = threadIdx.x + it * BLK;
      if (s < NSLOT) {
        int pix = s >> 2, q = s & 3;
        *reinterpret_cast<uint4*>(lds + pix * 40 + q * 8) = R[it];
      }
    }
  }
};

// --------------------------------------------------------- MFMA 3x3 conv
// block: 128 linear pixels x (MTW*2*16) ocs.  4 waves in 2x2 (wm, wn).
// MODE 0: relu(bn)  MODE 1: bn+res  MODE 2: relu(bn+res)
// OUTBF 1: write bf16 [pix][COUT] (MODE 0 semantics) via LDS transpose
template <int W_IMG, int CIN, int MTW, int MODE, int OUTBF>
__global__ __launch_bounds__(BLK, 2) void conv3_bf(
    const __bf16* __restrict__ inT, const __bf16* __restrict__ wp,
    const float* __restrict__ gamma, const float* __restrict__ beta,
    const float* __restrict__ res, void* __restrict__ outv) {
  constexpr int ROWS = 128 / W_IMG + 4;
  constexpr int COLS = W_IMG + 2;
  constexpr int NPIX = W_IMG * W_IMG;
  constexpr int NCH  = CIN / 32;
  constexpr int MT_TOT = MTW * 2;
  constexpr int COUT = MT_TOT * 16;
  constexpr int TILE_E = ROWS * COLS * 40;
  constexpr int LDSE = (OUTBF && 128 * COUT > TILE_E) ? 128 * COUT : TILE_E;
  __shared__ __bf16 lds[LDSE];

  const int tid = threadIdx.x;
  const int lane = tid & 63, wv = tid >> 6;
  const int wm = wv >> 1, wn = wv & 1;
  const int quad = lane >> 4, li = lane & 15;
  const int img = blockIdx.y;
  const int P0 = blockIdx.x * 128;
  const int h0 = P0 / W_IMG;

  int basee[4]; int pstore[4]; bool pok[4];
#pragma unroll
  for (int nt = 0; nt < 4; ++nt) {
    int p = P0 + wn * 64 + nt * 16 + li;
    bool ok = p < NPIX;
    int p2 = ok ? p : (NPIX - 1);
    int h = p2 / W_IMG, w = p2 - h * W_IMG;
    basee[nt] = ((h - h0) * COLS + w) * 40 + quad * 8;
    pstore[nt] = p2; pok[nt] = ok;
  }

  f32x4 acc[MTW][4];
#pragma unroll
  for (int mt = 0; mt < MTW; ++mt)
#pragma unroll
    for (int nt = 0; nt < 4; ++nt) acc[mt][nt] = (f32x4){0.f, 0.f, 0.f, 0.f};

  const bf16x8* wp8 = reinterpret_cast<const bf16x8*>(wp);

  Stage<W_IMG, ROWS> st;
  st.load(inT, CIN, 0, img, h0);
  for (int q = 0; q < NCH; ++q) {
    __syncthreads();            // prior chunk fully consumed
    st.store(lds);              // vmcnt-wait + ds_write
    __syncthreads();
    if (q + 1 < NCH) st.load(inT, CIN, (q + 1) * 32, img, h0);  // async under MFMAs
#pragma unroll
    for (int t = 0; t < 9; ++t) {
      const int toff = ((t / 3) * COLS + (t % 3)) * 40;
      bf16x8 wf[MTW];
#pragma unroll
      for (int mt = 0; mt < MTW; ++mt)
        wf[mt] = wp8[(size_t)((q * 9 + t) * MT_TOT + wm * MTW + mt) * 64 + lane];
      bf16x8 xf[4];
#pragma unroll
      for (int nt = 0; nt < 4; ++nt)
        xf[nt] = *reinterpret_cast<const bf16x8*>(&lds[basee[nt] + toff]);
#pragma unroll
      for (int mt = 0; mt < MTW; ++mt)
#pragma unroll
        for (int nt = 0; nt < 4; ++nt)
          acc[mt][nt] = __builtin_amdgcn_mfma_f32_16x16x32_bf16(wf[mt], xf[nt], acc[mt][nt], 0, 0, 0);
    }
  }

  if constexpr (!OUTBF) {
    float* out = (float*)outv;
#pragma unroll
    for (int mt = 0; mt < MTW; ++mt) {
#pragma unroll
      for (int r = 0; r < 4; ++r) {
        int oc = wm * MTW * 16 + mt * 16 + quad * 4 + r;
        float g = gamma[oc], bb = beta[oc];
#pragma unroll
        for (int nt = 0; nt < 4; ++nt) {
          if (!pok[nt]) continue;
          size_t idx = ((size_t)img * COUT + oc) * NPIX + pstore[nt];
          float v = acc[mt][nt][r] * g + bb;
          if constexpr (MODE == 1 || MODE == 2) v += res[idx];
          if constexpr (MODE == 0 || MODE == 2) v = fmaxf(v, 0.f);
          out[idx] = v;
        }
      }
    }
  } else {
    // bf16 [pix][COUT] output via swizzled LDS transpose -> coalesced 16B stores
    __bf16* outT = (__bf16*)outv;
    __syncthreads();  // tile reads done; reuse LDS
#pragma unroll
    for (int mt = 0; mt < MTW; ++mt) {
      int ocb = wm * MTW * 16 + mt * 16 + quad * 4;
      float g0 = gamma[ocb + 0], b0 = beta[ocb + 0];
      float g1 = gamma[ocb + 1], b1 = beta[ocb + 1];
      float g2 = gamma[ocb + 2], b2 = beta[ocb + 2];
      float g3 = gamma[ocb + 3], b3 = beta[ocb + 3];
#pragma unroll
      for (int nt = 0; nt < 4; ++nt) {
        if (!pok[nt]) continue;
        int pl = wn * 64 + nt * 16 + li;   // local pixel 0..127
        __bf16 o[4];
        o[0] = (__bf16)fmaxf(acc[mt][nt][0] * g0 + b0, 0.f);
        o[1] = (__bf16)fmaxf(acc[mt][nt][1] * g1 + b1, 0.f);
        o[2] = (__bf16)fmaxf(acc[mt][nt][2] * g2 + b2, 0.f);
        o[3] = (__bf16)fmaxf(acc[mt][nt][3] * g3 + b3, 0.f);
        int byt = pl * (COUT * 2) + ocb * 2;
        byt ^= (pl & 7) << 4;              // bank swizzle (row stride 256B)
        *reinterpret_cast<uint2*>(reinterpret_cast<char*>(lds) + byt) =
            *reinterpret_cast<uint2*>(o);
      }
    }
    __syncthreads();
    constexpr int SLOTS_ROW = COUT / 8;         // 16 (COUT=128)
    constexpr int ROWS_PASS = BLK / SLOTS_ROW;  // 16
#pragma unroll
    for (int pass = 0; pass < 128 / ROWS_PASS; ++pass) {
      int pl = pass * ROWS_PASS + (tid / SLOTS_ROW);
      int ss = tid % SLOTS_ROW;
      if (P0 + pl < NPIX) {
        int byt = pl * (COUT * 2) + ss * 16;
        byt ^= (pl & 7) << 4;
        uint4 vv = *reinterpret_cast<const uint4*>(reinterpret_cast<const char*>(lds) + byt);
        *reinterpret_cast<uint4*>(outT + ((size_t)img * NPIX + P0 + pl) * COUT + ss * 8) = vv;
      }
    }
  }
}

// ----------------- stride-2 3x3 MFMA conv: 56x56x64 -> 28x28x64, relu(bn), bf16 out
// block: 128 linear output pixels x 64 ocs. 4 waves 2x2 (wm=oc half, wn=pix half).
// 128 linear out-pixels span up to 6 output rows (h-h0 <= 5) -> input tile rows
// 2*h0-1 .. 2*h0+11 = 13 rows.
__global__ __launch_bounds__(BLK, 2) void conv_ba1_mfma(
    const __bf16* __restrict__ xT, const __bf16* __restrict__ wp,
    const float* __restrict__ gamma, const float* __restrict__ beta,
    __bf16* __restrict__ outT) {
  constexpr int WOUT = 28, NPIX = 784;
  constexpr int ROWS = 13, COLS = 58;
  constexpr int TILE_E = ROWS * COLS * 40; // 30160 bf16 (transpose buf 8192 fits inside)
  __shared__ __bf16 lds[TILE_E];

  const int tid = threadIdx.x;
  const int lane = tid & 63, wv = tid >> 6;
  const int wm = wv >> 1, wn = wv & 1;
  const int quad = lane >> 4, li = lane & 15;
  const int img = blockIdx.y;
  const int P0 = blockIdx.x * 128;
  const int h0 = P0 / WOUT;

  int basee[4]; bool pok[4];
#pragma unroll
  for (int nt = 0; nt < 4; ++nt) {
    int p = P0 + wn * 64 + nt * 16 + li;
    bool ok = p < NPIX;
    int p2 = ok ? p : (NPIX - 1);
    int h = p2 / WOUT, w = p2 - h * WOUT;
    // tap (dh,dw) reads input (2h-1+dh, 2w-1+dw) -> tile (2*(h-h0)+dh, 2w+dw)
    basee[nt] = (2 * (h - h0) * COLS + 2 * w) * 40 + quad * 8;
    pok[nt] = ok;
  }

  f32x4 acc[2][4];
#pragma unroll
  for (int mt = 0; mt < 2; ++mt)
#pragma unroll
    for (int nt = 0; nt < 4; ++nt) acc[mt][nt] = (f32x4){0.f, 0.f, 0.f, 0.f};

  const bf16x8* wp8 = reinterpret_cast<const bf16x8*>(wp);

  // Stage<56,13> with h0 param = 2*h0 gives tile row r -> input row 2*h0-1+r
  Stage<56, 13> st;
  st.load(xT, 64, 0, img, 2 * h0);
  for (int q = 0; q < 2; ++q) {
    __syncthreads();
    st.store(lds);
    __syncthreads();
    if (q == 0) st.load(xT, 64, 32, img, 2 * h0);
#pragma unroll
    for (int t = 0; t < 9; ++t) {
      const int toff = ((t / 3) * COLS + (t % 3)) * 40;
      bf16x8 wf[2];
#pragma unroll
      for (int mt = 0; mt < 2; ++mt)
        wf[mt] = wp8[(size_t)((q * 9 + t) * 4 + wm * 2 + mt) * 64 + lane];
      bf16x8 xf[4];
#pragma unroll
      for (int nt = 0; nt < 4; ++nt)
        xf[nt] = *reinterpret_cast<const bf16x8*>(&lds[basee[nt] + toff]);
#pragma unroll
      for (int mt = 0; mt < 2; ++mt)
#pragma unroll
        for (int nt = 0; nt < 4; ++nt)
          acc[mt][nt] = __builtin_amdgcn_mfma_f32_16x16x32_bf16(wf[mt], xf[nt], acc[mt][nt], 0, 0, 0);
    }
  }

  // epilogue: relu(bn) -> bf16 [pix][64] via swizzled LDS transpose
  __syncthreads();
#pragma unroll
  for (int mt = 0; mt < 2; ++mt) {
    int ocb = wm * 32 + mt * 16 + quad * 4;
    float g0 = gamma[ocb + 0], b0 = beta[ocb + 0];
    float g1 = gamma[ocb + 1], b1 = beta[ocb + 1];
    float g2 = gamma[ocb + 2], b2 = beta[ocb + 2];
    float g3 = gamma[ocb + 3], b3 = beta[ocb + 3];
#pragma unroll
    for (int nt = 0; nt < 4; ++nt) {
      if (!pok[nt]) continue;
      int pl = wn * 64 + nt * 16 + li;
      __bf16 o[4];
      o[0] = (__bf16)fmaxf(acc[mt][nt][0] * g0 + b0, 0.f);
      o[1] = (__bf16)fmaxf(acc[mt][nt][1] * g1 + b1, 0.f);
      o[2] = (__bf16)fmaxf(acc[mt][nt][2] * g2 + b2, 0.f);
      o[3] = (__bf16)fmaxf(acc[mt][nt][3] * g3 + b3, 0.f);
      int byt = pl * 128 + ocb * 2;
      byt ^= (pl & 7) << 4;
      *reinterpret_cast<uint2*>(reinterpret_cast<char*>(lds) + byt) =
          *reinterpret_cast<uint2*>(o);
    }
  }
  __syncthreads();
#pragma unroll
  for (int pass = 0; pass < 4; ++pass) {
    int pl = pass * 32 + (tid >> 3);
    int ss = tid & 7;
    if (P0 + pl < NPIX) {
      int byt = pl * 128 + ss * 16;
      byt ^= (pl & 7) << 4;
      uint4 vv = *reinterpret_cast<const uint4*>(reinterpret_cast<const char*>(lds) + byt);
      *reinterpret_cast<uint4*>(outT + ((size_t)img * NPIX + P0 + pl) * 64 + ss * 8) = vv;
    }
  }
}

// --------------------- fused x_big: bn(1x1(x)) + mask * bn(3x3(h_f)), MFMA
__global__ __launch_bounds__(BLK, 2) void conv_xbig_bf(
    const __bf16* __restrict__ hfT, const __bf16* __restrict__ xT,
    const __bf16* __restrict__ wp3, const __bf16* __restrict__ wp1,
    const float* __restrict__ g2v, const float* __restrict__ b2v,
    const float* __restrict__ gdv, const float* __restrict__ bdv,
    const float* __restrict__ maskv, float* __restrict__ out) {
  constexpr int W_IMG = 56, ROWS = 6, COLS = 58, NPIX = 3136;
  __shared__ __bf16 lds[ROWS * COLS * 40];

  const int tid = threadIdx.x;
  const int lane = tid & 63, wv = tid >> 6;
  const int wm = wv >> 1, wn = wv & 1;
  const int quad = lane >> 4, li = lane & 15;
  const int img = blockIdx.y;
  const int P0 = blockIdx.x * 128;
  const int h0 = P0 / W_IMG;
  const float m = maskv[img];

  int basee[4]; int pstore[4]; bool pok[4];
#pragma unroll
  for (int nt = 0; nt < 4; ++nt) {
    int p = P0 + wn * 64 + nt * 16 + li;
    bool ok = p < NPIX;
    int p2 = ok ? p : (NPIX - 1);
    int h = p2 / W_IMG, w = p2 - h * W_IMG;
    basee[nt] = ((h - h0) * COLS + w) * 40 + quad * 8;
    pstore[nt] = p2; pok[nt] = ok;
  }

  f32x4 acc3[4][4], acc1[4][4];
#pragma unroll
  for (int mt = 0; mt < 4; ++mt)
#pragma unroll
    for (int nt = 0; nt < 4; ++nt) {
      acc3[mt][nt] = (f32x4){0.f, 0.f, 0.f, 0.f};
      acc1[mt][nt] = (f32x4){0.f, 0.f, 0.f, 0.f};
    }

  const bf16x8* wp3v = reinterpret_cast<const bf16x8*>(wp3);
  const bf16x8* wp1v = reinterpret_cast<const bf16x8*>(wp1);

  Stage<56, 6> st;
  st.load(hfT, 128, 0, img, h0);

  // phase 1: 3x3 over h_f, CIN=128
  for (int q = 0; q < 4; ++q) {
    __syncthreads();
    st.store(lds);
    __syncthreads();
    if (q < 3) st.load(hfT, 128, (q + 1) * 32, img, h0);
    else       st.load(xT, 64, 0, img, h0);
#pragma unroll
    for (int t = 0; t < 9; ++t) {
      const int toff = ((t / 3) * COLS + (t % 3)) * 40;
      bf16x8 wf[4];
#pragma unroll
      for (int mt = 0; mt < 4; ++mt)
        wf[mt] = wp3v[(size_t)(((q * 9 + t) * 8) + wm * 4 + mt) * 64 + lane];
      bf16x8 xf[4];
#pragma unroll
      for (int nt = 0; nt < 4; ++nt)
        xf[nt] = *reinterpret_cast<const bf16x8*>(&lds[basee[nt] + toff]);
#pragma unroll
      for (int mt = 0; mt < 4; ++mt)
#pragma unroll
        for (int nt = 0; nt < 4; ++nt)
          acc3[mt][nt] = __builtin_amdgcn_mfma_f32_16x16x32_bf16(wf[mt], xf[nt], acc3[mt][nt], 0, 0, 0);
    }
  }

  // phase 2: 1x1 over x, CIN=64 (center tap)
  for (int q = 0; q < 2; ++q) {
    __syncthreads();
    st.store(lds);
    __syncthreads();
    if (q == 0) st.load(xT, 64, 32, img, h0);
    const int toff = (1 * COLS + 1) * 40;
    bf16x8 wf[4];
#pragma unroll
    for (int mt = 0; mt < 4; ++mt)
      wf[mt] = wp1v[(size_t)((q * 8) + wm * 4 + mt) * 64 + lane];
    bf16x8 xf[4];
#pragma unroll
    for (int nt = 0; nt < 4; ++nt)
      xf[nt] = *reinterpret_cast<const bf16x8*>(&lds[basee[nt] + toff]);
#pragma unroll
    for (int mt = 0; mt < 4; ++mt)
#pragma unroll
      for (int nt = 0; nt < 4; ++nt)
        acc1[mt][nt] = __builtin_amdgcn_mfma_f32_16x16x32_bf16(wf[mt], xf[nt], acc1[mt][nt], 0, 0, 0);
  }

#pragma unroll
  for (int mt = 0; mt < 4; ++mt) {
#pragma unroll
    for (int r = 0; r < 4; ++r) {
      int oc = wm * 64 + mt * 16 + quad * 4 + r;
      float g2 = g2v[oc], b2 = b2v[oc], gd = gdv[oc], bd = bdv[oc];
#pragma unroll
      for (int nt = 0; nt < 4; ++nt) {
        if (!pok[nt]) continue;
        size_t idx = ((size_t)img * 128 + oc) * NPIX + pstore[nt];
        float v = (acc1[mt][nt][r] * gd + bd) + m * (acc3[mt][nt][r] * g2 + b2);
        out[idx] = v;
      }
    }
  }
}

// --------------------------------------------- base_transform 1x1 conv + bn
__global__ __launch_bounds__(BLK) void conv1x1_bt_k(
    const float* __restrict__ xl, const float* __restrict__ w,
    const float* __restrict__ g, const float* __restrict__ bt, float* __restrict__ out) {
  const int b = blockIdx.z;
  const int oc0 = blockIdx.y * 8;
  const float* __restrict__ xp = xl + (size_t)b * 64 * 784;
  float gr[8], br[8];
#pragma unroll
  for (int j = 0; j < 8; ++j) {
    gr[j] = g[oc0 + j];
    br[j] = bt[oc0 + j];
  }
  for (int p = (int)threadIdx.x; p < 784; p += BLK) {
    float acc[8];
#pragma unroll
    for (int j = 0; j < 8; ++j) acc[j] = 0.f;
    for (int c = 0; c < 64; ++c) {
      float xv = xp[c * 784 + p];
#pragma unroll
      for (int j = 0; j < 8; ++j) acc[j] += xv * w[(oc0 + j) * 64 + c];
    }
#pragma unroll
    for (int j = 0; j < 8; ++j)
      out[(size_t)(b * 128 + oc0 + j) * 784 + p] = acc[j] * gr[j] + br[j];
  }
}

// ------------------------------------- GAP of (x_big + upsampled x_little)
__global__ __launch_bounds__(BLK) void gap2_k(const float* __restrict__ xbig,
                                              const float* __restrict__ xlbt,
                                              float* __restrict__ ysum) {
  __shared__ float sm1[4], sm2[4];
  const int bo = blockIdx.x;
  const float4* p4 = reinterpret_cast<const float4*>(xbig + (size_t)bo * 3136);
  float s1 = 0.f;
  for (int i = threadIdx.x; i < 784; i += BLK) {
    float4 v = p4[i];
    s1 += (v.x + v.y) + (v.z + v.w);
  }
  const float4* q4 = reinterpret_cast<const float4*>(xlbt + (size_t)bo * 784);
  float s2 = 0.f;
  for (int i = threadIdx.x; i < 196; i += BLK) {
    float4 v = q4[i];
    s2 += (v.x + v.y) + (v.z + v.w);
  }
  s1 = block_reduce_sum(s1, sm1);
  s2 = block_reduce_sum(s2, sm2);
  if (threadIdx.x == 0) ysum[bo] = s1 * (1.f / 3136.f) + s2 * (1.f / 784.f);
}

// ----------------------------------------------------- SE attention weights
__global__ void att_k(const float* __restrict__ ysum, const float* __restrict__ w1,
                      const float* __restrict__ w2, float* __restrict__ att) {
  int b = blockIdx.x;
  int t = threadIdx.x;
  __shared__ float hid[8];
  __shared__ float ybuf[128];
  ybuf[t] = ysum[b * 128 + t];
  __syncthreads();
  if (t < 8) {
    float s = 0.f;
    for (int c = 0; c < 128; ++c) s += ybuf[c] * w1[t * 128 + c];
    hid[t] = fmaxf(s, 0.f);
  }
  __syncthreads();
  float s = 0.f;
#pragma unroll
  for (int j = 0; j < 8; ++j) s += hid[j] * w2[t * 8 + j];
  att[b * 128 + t] = 1.f / (1.f + expf(-s));
}

// ------------------------------- SE combine: relu(a*xl_up + (1-a)*x_big)
__global__ __launch_bounds__(BLK) void se_k(const float* __restrict__ xlbt,
                                            const float* __restrict__ att,
                                            float* __restrict__ out) {
  int idx = blockIdx.x * BLK + threadIdx.x;
  int p = idx % 3136;
  int bo = idx / 3136;
  int h = p / 56, w = p % 56;
  float a = att[bo];
  float xl = xlbt[(size_t)bo * 784 + (h >> 1) * 28 + (w >> 1)];
  float xb = out[idx];
  out[idx] = fmaxf(a * xl + (1.f - a) * xb, 0.f);
}

// ---------------------------------------------------------------- launcher
extern "C" void kernel_launch(void* const* d_in, const int* in_sizes, int n_in,
                              void* d_out, int out_size, void* d_ws, size_t ws_size,
                              hipStream_t stream) {
  const float* x      = (const float*)d_in[0];
  const float* gumbel = (const float*)d_in[1];
  const float* nav_w  = (const float*)d_in[2];
  const float* nbg    = (const float*)d_in[3];
  const float* nbb    = (const float*)d_in[4];
  const float* gsw    = (const float*)d_in[5];
  const float* gsb    = (const float*)d_in[6];
  const float* ba_w1  = (const float*)d_in[7];
  const float* ba_g1  = (const float*)d_in[8];
  const float* ba_b1  = (const float*)d_in[9];
  const float* ba_w2  = (const float*)d_in[10];
  const float* ba_g2  = (const float*)d_in[11];
  const float* ba_b2  = (const float*)d_in[12];
  const float* bf_wd  = (const float*)d_in[13];
  const float* bf_gd  = (const float*)d_in[14];
  const float* bf_bd  = (const float*)d_in[15];
  const float* bf_w1  = (const float*)d_in[16];
  const float* bf_g1  = (const float*)d_in[17];
  const float* bf_b1  = (const float*)d_in[18];
  const float* bf_w2  = (const float*)d_in[19];
  const float* bf_g2  = (const float*)d_in[20];
  const float* bf_b2  = (const float*)d_in[21];
  const float* bt_w   = (const float*)d_in[22];
  const float* bt_g   = (const float*)d_in[23];
  const float* bt_b   = (const float*)d_in[24];
  const float* att_w1 = (const float*)d_in[25];
  const float* att_w2 = (const float*)d_in[26];
  const float* fu_w1  = (const float*)d_in[27];
  const float* fu_g1  = (const float*)d_in[28];
  const float* fu_b1  = (const float*)d_in[29];
  const float* fu_w2  = (const float*)d_in[30];
  const float* fu_g2  = (const float*)d_in[31];
  const float* fu_b2  = (const float*)d_in[32];

  float* out = (float*)d_out;
  float* ws  = (float*)d_ws;

  const size_t N_OUT = 51380224;  // 128*128*56*56
  float* bufA = ws;               // 51.38M-float region, re-purposed for bf16 buffers:
  //   A1 [0, 25690112): hfbf then hfubf  (51,380,224 bf16 = [img][3136][128])
  //   A2 [25690112, 51380224): xbf (25,690,112 bf16 = [img][3136][64]) then outbf
  __bf16* hfbf  = (__bf16*)bufA;
  __bf16* hfubf = (__bf16*)bufA;
  __bf16* xbf   = (__bf16*)(bufA + 25690112);
  __bf16* outbf = (__bf16*)(bufA + 25690112);
  float* xlbt = bufA + N_OUT;     // [128,128,28,28]
  float* resl = xlbt + 12845056;  // res_l -> x_little
  __bf16* habf = (__bf16*)(resl + 6422528);  // [128,784,64] bf16
  float* ygap = resl + 6422528 + 6422528;    // [128,64]
  float* mskv = ygap + 8192;      // [128]
  float* ysum = mskv + 128;       // [128,128]
  float* attb = ysum + 16384;     // [128,128]
  float* wend = attb + 16384;
  // bf16 weight packs (sizes in floats = bf16elems/2)
  __bf16* wsW1 = (__bf16*)(wend);                 // 73728 bf16
  __bf16* wsW2 = (__bf16*)(wend + 36864);         // 147456 bf16
  __bf16* wsF1 = (__bf16*)(wend + 110592);        // 147456 bf16
  __bf16* wsF2 = (__bf16*)(wend + 184320);        // 147456 bf16
  __bf16* wsA2 = (__bf16*)(wend + 258048);        // 36864 bf16
  __bf16* wsWd = (__bf16*)(wend + 276480);        // 8192 bf16
  __bf16* wsA1 = (__bf16*)(wend + 280576);        // 36864 bf16 (ba_w1 pack)
  float* mask_out = out + ((size_t)out_size - 128);

  // weight prepack (bf16 fragment layout)
  pack3_k<<<36, BLK, 0, stream>>>(bf_w1, wsW1, 64, 8);
  pack3_k<<<72, BLK, 0, stream>>>(bf_w2, wsW2, 128, 8);
  pack3_k<<<72, BLK, 0, stream>>>(fu_w1, wsF1, 128, 8);
  pack3_k<<<72, BLK, 0, stream>>>(fu_w2, wsF2, 128, 8);
  pack3_k<<<18, BLK, 0, stream>>>(ba_w2, wsA2, 64, 4);
  pack3_k<<<18, BLK, 0, stream>>>(ba_w1, wsA1, 64, 4);
  pack1_k<<<4, BLK, 0, stream>>>(bf_wd, wsWd, 64, 8);

  // x -> bf16 [pix][64]
  txp_k<64><<<dim3(49, 128), BLK, 0, stream>>>(x, xbf, 3136);

  // navigation mask
  gap_x_k<<<8192, BLK, 0, stream>>>(x, ygap);
  mask_k<<<1, 128, 0, stream>>>(ygap, gumbel, nav_w, nbg, nbb, gsw, gsb, mskv, mask_out);

  // ample branch
  avgpool_k<<<25088, BLK, 0, stream>>>(x, resl);
  conv_ba1_mfma<<<dim3(7, 128), BLK, 0, stream>>>(xbf, wsA1, ba_g1, ba_b1, habf);
  conv3_bf<28, 64, 2, 1, 0><<<dim3(7, 128), BLK, 0, stream>>>(
      habf, wsA2, ba_g2, ba_b2, resl, resl);
  conv1x1_bt_k<<<dim3(1, 16, 128), BLK, 0, stream>>>(resl, bt_w, bt_g, bt_b, xlbt);

  // focal branch
  conv3_bf<56, 64, 4, 0, 1><<<dim3(25, 128), BLK, 0, stream>>>(
      xbf, wsW1, bf_g1, bf_b1, nullptr, hfbf);
  conv_xbig_bf<<<dim3(25, 128), BLK, 0, stream>>>(
      hfbf, xbf, wsW2, wsWd, bf_g2, bf_b2, bf_gd, bf_bd, mskv, out);

  // SE fusion
  gap2_k<<<16384, BLK, 0, stream>>>(out, xlbt, ysum);
  att_k<<<128, 128, 0, stream>>>(ysum, att_w1, att_w2, attb);
  se_k<<<200704, BLK, 0, stream>>>(xlbt, attb, out);

  // out -> bf16 [pix][128]  (xbf is dead now; reuse A2)
  txp_k<128><<<dim3(49, 128), BLK, 0, stream>>>(out, outbf, 3136);

  // fusion residual block
  conv3_bf<56, 128, 4, 0, 1><<<dim3(25, 128), BLK, 0, stream>>>(
      outbf, wsF1, fu_g1, fu_b1, nullptr, hfubf);
  conv3_bf<56, 128, 4, 2, 0><<<dim3(25, 128), BLK, 0, stream>>>(
      hfubf, wsF2, fu_g2, fu_b2, out, out);
}

// Round 4
// 1859.761 us; speedup vs baseline: 1.8548x; 1.0586x over previous
//
#include <hip/hip_runtime.h>
#include <cstdint>
#include <cstddef>

#define BLK 256

typedef __bf16 bf16x8 __attribute__((ext_vector_type(8)));
typedef float  f32x4  __attribute__((ext_vector_type(4)));

// ---------------------------------------------------------------- reductions
__device__ __forceinline__ float block_reduce_sum(float v, float* sm) {
#pragma unroll
  for (int off = 32; off > 0; off >>= 1) v += __shfl_down(v, off, 64);
  const int lane = threadIdx.x & 63;
  const int wid  = threadIdx.x >> 6;
  if (lane == 0) sm[wid] = v;
  __syncthreads();
  v = sm[0] + sm[1] + sm[2] + sm[3];
  __syncthreads();
  return v;
}

// ------------------------------------------------------- global average pool
__global__ __launch_bounds__(BLK) void gap_x_k(const float* __restrict__ x,
                                               float* __restrict__ y) {
  __shared__ float sm[4];
  const float4* p4 = reinterpret_cast<const float4*>(x + (size_t)blockIdx.x * 3136);
  float s = 0.f;
  for (int i = threadIdx.x; i < 784; i += BLK) {
    float4 v = p4[i];
    s += (v.x + v.y) + (v.z + v.w);
  }
  s = block_reduce_sum(s, sm);
  if (threadIdx.x == 0) y[blockIdx.x] = s * (1.f / 3136.f);
}

// ------------------------------------------------------------ gumbel mask
__global__ void mask_k(const float* __restrict__ y, const float* __restrict__ gumbel,
                       const float* __restrict__ nav_w, const float* __restrict__ nbg,
                       const float* __restrict__ nbb, const float* __restrict__ gsw,
                       const float* __restrict__ gsb, float* __restrict__ maskv,
                       float* __restrict__ mask_out) {
  int b = threadIdx.x;
  float d0 = 0.f, d1 = 0.f;
  for (int c = 0; c < 64; ++c) {
    float yv = y[b * 64 + c];
    d0 += yv * nav_w[c];
    d1 += yv * nav_w[64 + c];
  }
  float g0 = fmaxf(d0 * nbg[0] + nbb[0], 0.f);
  float g1 = fmaxf(d1 * nbg[1] + nbb[1], 0.f);
  int vid = b >> 3, s = b & 7;
  float l0 = gsw[s * 4 + 0] * g0 + gsw[s * 4 + 1] * g1 + gsb[s * 2 + 0] + gumbel[(vid * 8 + s) * 2 + 0];
  float l1 = gsw[s * 4 + 2] * g0 + gsw[s * 4 + 3] * g1 + gsb[s * 2 + 1] + gumbel[(vid * 8 + s) * 2 + 1];
  float m = (l1 > l0) ? 1.f : 0.f;
  maskv[b] = m;
  mask_out[b] = m;
}

// ------------------------------------------------ avgpool 3x3 s2 p1
__global__ __launch_bounds__(BLK) void avgpool_k(const float* __restrict__ x,
                                                 float* __restrict__ out) {
  int idx = blockIdx.x * BLK + threadIdx.x;
  int p = idx % 784;
  int bc = idx / 784;
  int h = p / 28, w = p % 28;
  const float* xp = x + (size_t)bc * 3136;
  int h0 = 2 * h - 1, w0 = 2 * w - 1;
  float s = 0.f;
#pragma unroll
  for (int i = 0; i < 3; ++i) {
    int hh = h0 + i;
    if (hh < 0 || hh >= 56) continue;
#pragma unroll
    for (int j = 0; j < 3; ++j) {
      int ww = w0 + j;
      if (ww < 0 || ww >= 56) continue;
      s += xp[hh * 56 + ww];
    }
  }
  out[idx] = s * (1.f / 9.f);
}

// ---------------------------------------------- fp32->bf16 [ch][pix] -> [pix][ch]
template <int C>
__global__ __launch_bounds__(BLK) void txp_k(const float* __restrict__ src,
                                             __bf16* __restrict__ dst, int NP) {
  __shared__ float t[C * 65];
  const int b = blockIdx.y;
  const int p0 = blockIdx.x * 64;
  for (int i = threadIdx.x; i < C * 64; i += BLK) {
    int c = i >> 6, p = i & 63;
    float v = 0.f;
    if (p0 + p < NP) v = src[((size_t)b * C + c) * NP + p0 + p];
    t[c * 65 + p] = v;
  }
  __syncthreads();
  constexpr int CQ = C / 8;
  for (int i = threadIdx.x; i < 64 * CQ; i += BLK) {
    int cq = i % CQ, pix = i / CQ;
    if (p0 + pix < NP) {
      __bf16 o[8];
#pragma unroll
      for (int j = 0; j < 8; ++j) o[j] = (__bf16)t[(cq * 8 + j) * 65 + pix];
      *reinterpret_cast<uint4*>(dst + ((size_t)b * NP + p0 + pix) * C + cq * 8) =
          *reinterpret_cast<uint4*>(o);
    }
  }
}

// ------------------------------------------------------- weight prepack (3x3)
__global__ void pack3_k(const float* __restrict__ w, __bf16* __restrict__ dst,
                        int CIN, int MT) {
  int total = (CIN / 32) * 9 * MT * 64;
  int idx = blockIdx.x * BLK + threadIdx.x;
  if (idx >= total) return;
  int lane = idx & 63;
  int g = idx >> 6;
  int mt = g % MT; g /= MT;
  int t = g % 9;  int q = g / 9;
  int oc = mt * 16 + (lane & 15);
  int quad = lane >> 4;
#pragma unroll
  for (int j = 0; j < 8; ++j) {
    int c = q * 32 + quad * 8 + j;
    dst[(size_t)idx * 8 + j] = (__bf16)w[((size_t)oc * CIN + c) * 9 + t];
  }
}

// 1x1 variant
__global__ void pack1_k(const float* __restrict__ w, __bf16* __restrict__ dst,
                        int CIN, int MT) {
  int total = (CIN / 32) * MT * 64;
  int idx = blockIdx.x * BLK + threadIdx.x;
  if (idx >= total) return;
  int lane = idx & 63;
  int g = idx >> 6;
  int mt = g % MT;
  int q = g / MT;
  int oc = mt * 16 + (lane & 15);
  int quad = lane >> 4;
#pragma unroll
  for (int j = 0; j < 8; ++j) {
    int c = q * 32 + quad * 8 + j;
    dst[(size_t)idx * 8 + j] = (__bf16)w[(size_t)oc * CIN + c];
  }
}

// ------------------------------------------------ staging: bf16 [pix][ch] -> regs -> LDS
// LDS tile: [pix][32ch] bf16, pixel stride 40 (pad 8).  One 16B slot = 8 channels.
template <int W_IMG, int ROWS>
struct Stage {
  static constexpr int COLS  = W_IMG + 2;
  static constexpr int NSLOT = ROWS * COLS * 4;
  static constexpr int NIT   = (NSLOT + BLK - 1) / BLK;
  uint4 R[NIT];

  __device__ __forceinline__ void load(const __bf16* __restrict__ inT, int CIN, int c0,
                                       int img, int h0) {
    constexpr int NPIX = W_IMG * W_IMG;
#pragma unroll
    for (int it = 0; it < NIT; ++it) {
      int s = threadIdx.x + it * BLK;
      uint4 v{0u, 0u, 0u, 0u};
      if (s < NSLOT) {
        int pix = s >> 2, q = s & 3;
        int r = pix / COLS, cc = pix - r * COLS;
        int gh = h0 - 1 + r, gw = cc - 1;
        if (gh >= 0 && gh < W_IMG && gw >= 0 && gw < W_IMG)
          v = *reinterpret_cast<const uint4*>(
              inT + ((size_t)img * NPIX + gh * W_IMG + gw) * CIN + c0 + q * 8);
      }
      R[it] = v;
    }
  }

  __device__ __forceinline__ void store(__bf16* lds) {
#pragma unroll
    for (int it = 0; it < NIT; ++it) {
      int s = threadIdx.x + it * BLK;
      if (s < NSLOT) {
        int pix = s >> 2, q = s & 3;
        *reinterpret_cast<uint4*>(lds + pix * 40 + q * 8) = R[it];
      }
    }
  }
};

// --------------------------------------------------------- MFMA 3x3 conv (oc-split)
// block: 128 linear pixels x (MTW*2*16) ocs, gridDim.z oc-split.
// 4 waves in 2x2 (wm, wn).  Per-chunk weights hoisted to regs (double-buffered)
// BEFORE staging loads are issued -> weight waits never drain the staging prefetch.
// MODE 0: relu(bn)  MODE 1: bn+res  MODE 2: relu(bn+res)
// OUTBF 1: write bf16 [pix][COUT_G] (MODE 0 semantics) via LDS transpose
template <int W_IMG, int CIN, int MTW, int MODE, int OUTBF, int NSPLIT>
__global__ __launch_bounds__(BLK, 2) void conv3s_bf(
    const __bf16* __restrict__ inT, const __bf16* __restrict__ wp,
    const float* __restrict__ gamma, const float* __restrict__ beta,
    const float* __restrict__ res, void* __restrict__ outv) {
  constexpr int ROWS = 128 / W_IMG + 4;
  constexpr int COLS = W_IMG + 2;
  constexpr int NPIX = W_IMG * W_IMG;
  constexpr int NCH  = CIN / 32;          // always even (2 or 4)
  constexpr int MT_TOT = MTW * 2;         // per block
  constexpr int COUT_B = MT_TOT * 16;     // per block
  constexpr int COUT_G = COUT_B * NSPLIT; // global
  constexpr int MT_TOTG = COUT_G / 16;
  constexpr int NT = (NPIX + 127) / 128;
  constexpr int TILE_E = ROWS * COLS * 40;
  constexpr int LDSE = (OUTBF && 128 * COUT_B > TILE_E) ? 128 * COUT_B : TILE_E;
  __shared__ __bf16 lds[LDSE];

  const int tid = threadIdx.x;
  const int lane = tid & 63, wv = tid >> 6;
  const int wm = wv >> 1, wn = wv & 1;
  const int quad = lane >> 4, li = lane & 15;

  // XCD-aware swizzle: same-XCD gets contiguous (img,tile) range; oc-halves paired.
  const int F = blockIdx.x + NT * (blockIdx.y + 128 * blockIdx.z);
  constexpr int TOT = NT * 128 * NSPLIT;  // divisible by 8
  int Wk = (F & 7) * (TOT >> 3) + (F >> 3);
  int bz, u;
  if constexpr (NSPLIT == 2) { bz = Wk & 1; u = Wk >> 1; }
  else                       { bz = 0;      u = Wk;      }
  const int img  = u / NT;
  const int tile = u - img * NT;
  const int P0 = tile * 128;
  const int h0 = P0 / W_IMG;
  const int mtg0 = bz * MT_TOT + wm * MTW;

  int basee[4]; int pstore[4]; bool pok[4];
#pragma unroll
  for (int nt = 0; nt < 4; ++nt) {
    int p = P0 + wn * 64 + nt * 16 + li;
    bool ok = p < NPIX;
    int p2 = ok ? p : (NPIX - 1);
    int h = p2 / W_IMG, w = p2 - h * W_IMG;
    basee[nt] = ((h - h0) * COLS + w) * 40 + quad * 8;
    pstore[nt] = p2; pok[nt] = ok;
  }

  f32x4 acc[MTW][4];
#pragma unroll
  for (int mt = 0; mt < MTW; ++mt)
#pragma unroll
    for (int nt = 0; nt < 4; ++nt) acc[mt][nt] = (f32x4){0.f, 0.f, 0.f, 0.f};

  const bf16x8* wp8 = reinterpret_cast<const bf16x8*>(wp);

  bf16x8 wA[9 * MTW], wB[9 * MTW];
  auto LOADW = [&](bf16x8 (&wr)[9 * MTW], int q) {
#pragma unroll
    for (int t = 0; t < 9; ++t)
#pragma unroll
      for (int mt = 0; mt < MTW; ++mt)
        wr[t * MTW + mt] = wp8[(size_t)((q * 9 + t) * MT_TOTG + mtg0 + mt) * 64 + lane];
  };
  auto TAPS = [&](const bf16x8 (&wr)[9 * MTW]) {
#pragma unroll
    for (int t = 0; t < 9; ++t) {
      const int toff = ((t / 3) * COLS + (t % 3)) * 40;
      bf16x8 xf[4];
#pragma unroll
      for (int nt = 0; nt < 4; ++nt)
        xf[nt] = *reinterpret_cast<const bf16x8*>(&lds[basee[nt] + toff]);
#pragma unroll
      for (int mt = 0; mt < MTW; ++mt)
#pragma unroll
        for (int nt = 0; nt < 4; ++nt)
          acc[mt][nt] = __builtin_amdgcn_mfma_f32_16x16x32_bf16(wr[t * MTW + mt], xf[nt], acc[mt][nt], 0, 0, 0);
    }
  };

  Stage<W_IMG, ROWS> st;
  LOADW(wA, 0);
  __builtin_amdgcn_sched_barrier(0);   // weights issue before staging (vmcnt FIFO)
  st.load(inT, CIN, 0, img, h0);
  for (int q = 0; q < NCH; q += 2) {
    __syncthreads();
    st.store(lds);
    __syncthreads();
    if (q + 1 < NCH) { st.load(inT, CIN, (q + 1) * 32, img, h0); LOADW(wB, q + 1); }
    TAPS(wA);
    __syncthreads();
    st.store(lds);
    __syncthreads();
    if (q + 2 < NCH) { st.load(inT, CIN, (q + 2) * 32, img, h0); LOADW(wA, q + 2); }
    TAPS(wB);
  }

  if constexpr (!OUTBF) {
    float* out = (float*)outv;
#pragma unroll
    for (int mt = 0; mt < MTW; ++mt) {
#pragma unroll
      for (int r = 0; r < 4; ++r) {
        int oc = bz * COUT_B + wm * MTW * 16 + mt * 16 + quad * 4 + r;
        float g = gamma[oc], bb = beta[oc];
#pragma unroll
        for (int nt = 0; nt < 4; ++nt) {
          if (!pok[nt]) continue;
          size_t idx = ((size_t)img * COUT_G + oc) * NPIX + pstore[nt];
          float v = acc[mt][nt][r] * g + bb;
          if constexpr (MODE == 1 || MODE == 2) v += res[idx];
          if constexpr (MODE == 0 || MODE == 2) v = fmaxf(v, 0.f);
          out[idx] = v;
        }
      }
    }
  } else {
    // bf16 [pix][COUT_G] output via swizzled LDS transpose -> coalesced 16B stores
    __bf16* outT = (__bf16*)outv;
    __syncthreads();  // tile reads done; reuse LDS
#pragma unroll
    for (int mt = 0; mt < MTW; ++mt) {
      int ocl = wm * MTW * 16 + mt * 16 + quad * 4;   // local 0..COUT_B-1
      int ocg = bz * COUT_B + ocl;
      float g0 = gamma[ocg + 0], b0 = beta[ocg + 0];
      float g1 = gamma[ocg + 1], b1 = beta[ocg + 1];
      float g2 = gamma[ocg + 2], b2 = beta[ocg + 2];
      float g3 = gamma[ocg + 3], b3 = beta[ocg + 3];
#pragma unroll
      for (int nt = 0; nt < 4; ++nt) {
        if (!pok[nt]) continue;
        int pl = wn * 64 + nt * 16 + li;   // local pixel 0..127
        __bf16 o[4];
        o[0] = (__bf16)fmaxf(acc[mt][nt][0] * g0 + b0, 0.f);
        o[1] = (__bf16)fmaxf(acc[mt][nt][1] * g1 + b1, 0.f);
        o[2] = (__bf16)fmaxf(acc[mt][nt][2] * g2 + b2, 0.f);
        o[3] = (__bf16)fmaxf(acc[mt][nt][3] * g3 + b3, 0.f);
        int byt = pl * (COUT_B * 2) + ocl * 2;
        byt ^= (pl & 7) << 4;              // bank swizzle (row stride 128B)
        *reinterpret_cast<uint2*>(reinterpret_cast<char*>(lds) + byt) =
            *reinterpret_cast<uint2*>(o);
      }
    }
    __syncthreads();
    constexpr int SLOTS_ROW = COUT_B / 8;       // 8
    constexpr int ROWS_PASS = BLK / SLOTS_ROW;  // 32
#pragma unroll
    for (int pass = 0; pass < 128 / ROWS_PASS; ++pass) {
      int pl = pass * ROWS_PASS + (tid / SLOTS_ROW);
      int ss = tid % SLOTS_ROW;
      if (P0 + pl < NPIX) {
        int byt = pl * (COUT_B * 2) + ss * 16;
        byt ^= (pl & 7) << 4;
        uint4 vv = *reinterpret_cast<const uint4*>(reinterpret_cast<const char*>(lds) + byt);
        *reinterpret_cast<uint4*>(outT + ((size_t)img * NPIX + P0 + pl) * COUT_G + bz * COUT_B + ss * 8) = vv;
      }
    }
  }
}

// ----------------- stride-2 3x3 MFMA conv: 56x56x64 -> 28x28x64, relu(bn), bf16 out
// block: 128 linear output pixels x 64 ocs. 4 waves 2x2.  Weight hoist per chunk.
__global__ __launch_bounds__(BLK, 2) void conv_ba1_mfma(
    const __bf16* __restrict__ xT, const __bf16* __restrict__ wp,
    const float* __restrict__ gamma, const float* __restrict__ beta,
    __bf16* __restrict__ outT) {
  constexpr int WOUT = 28, NPIX = 784;
  constexpr int ROWS = 13, COLS = 58;
  constexpr int TILE_E = ROWS * COLS * 40;
  __shared__ __bf16 lds[TILE_E];

  const int tid = threadIdx.x;
  const int lane = tid & 63, wv = tid >> 6;
  const int wm = wv >> 1, wn = wv & 1;
  const int quad = lane >> 4, li = lane & 15;
  const int img = blockIdx.y;
  const int P0 = blockIdx.x * 128;
  const int h0 = P0 / WOUT;

  int basee[4]; bool pok[4];
#pragma unroll
  for (int nt = 0; nt < 4; ++nt) {
    int p = P0 + wn * 64 + nt * 16 + li;
    bool ok = p < NPIX;
    int p2 = ok ? p : (NPIX - 1);
    int h = p2 / WOUT, w = p2 - h * WOUT;
    basee[nt] = (2 * (h - h0) * COLS + 2 * w) * 40 + quad * 8;
    pok[nt] = ok;
  }

  f32x4 acc[2][4];
#pragma unroll
  for (int mt = 0; mt < 2; ++mt)
#pragma unroll
    for (int nt = 0; nt < 4; ++nt) acc[mt][nt] = (f32x4){0.f, 0.f, 0.f, 0.f};

  const bf16x8* wp8 = reinterpret_cast<const bf16x8*>(wp);

  bf16x8 wr[18];
  Stage<56, 13> st;
  st.load(xT, 64, 0, img, 2 * h0);
  for (int q = 0; q < 2; ++q) {
    __syncthreads();
    st.store(lds);
    __syncthreads();
#pragma unroll
    for (int t = 0; t < 9; ++t)
#pragma unroll
      for (int mt = 0; mt < 2; ++mt)
        wr[t * 2 + mt] = wp8[(size_t)((q * 9 + t) * 4 + wm * 2 + mt) * 64 + lane];
    __builtin_amdgcn_sched_barrier(0);
    if (q == 0) st.load(xT, 64, 32, img, 2 * h0);
#pragma unroll
    for (int t = 0; t < 9; ++t) {
      const int toff = ((t / 3) * COLS + (t % 3)) * 40;
      bf16x8 xf[4];
#pragma unroll
      for (int nt = 0; nt < 4; ++nt)
        xf[nt] = *reinterpret_cast<const bf16x8*>(&lds[basee[nt] + toff]);
#pragma unroll
      for (int mt = 0; mt < 2; ++mt)
#pragma unroll
        for (int nt = 0; nt < 4; ++nt)
          acc[mt][nt] = __builtin_amdgcn_mfma_f32_16x16x32_bf16(wr[t * 2 + mt], xf[nt], acc[mt][nt], 0, 0, 0);
    }
  }

  // epilogue: relu(bn) -> bf16 [pix][64] via swizzled LDS transpose
  __syncthreads();
#pragma unroll
  for (int mt = 0; mt < 2; ++mt) {
    int ocb = wm * 32 + mt * 16 + quad * 4;
    float g0 = gamma[ocb + 0], b0 = beta[ocb + 0];
    float g1 = gamma[ocb + 1], b1 = beta[ocb + 1];
    float g2 = gamma[ocb + 2], b2 = beta[ocb + 2];
    float g3 = gamma[ocb + 3], b3 = beta[ocb + 3];
#pragma unroll
    for (int nt = 0; nt < 4; ++nt) {
      if (!pok[nt]) continue;
      int pl = wn * 64 + nt * 16 + li;
      __bf16 o[4];
      o[0] = (__bf16)fmaxf(acc[mt][nt][0] * g0 + b0, 0.f);
      o[1] = (__bf16)fmaxf(acc[mt][nt][1] * g1 + b1, 0.f);
      o[2] = (__bf16)fmaxf(acc[mt][nt][2] * g2 + b2, 0.f);
      o[3] = (__bf16)fmaxf(acc[mt][nt][3] * g3 + b3, 0.f);
      int byt = pl * 128 + ocb * 2;
      byt ^= (pl & 7) << 4;
      *reinterpret_cast<uint2*>(reinterpret_cast<char*>(lds) + byt) =
          *reinterpret_cast<uint2*>(o);
    }
  }
  __syncthreads();
#pragma unroll
  for (int pass = 0; pass < 4; ++pass) {
    int pl = pass * 32 + (tid >> 3);
    int ss = tid & 7;
    if (P0 + pl < NPIX) {
      int byt = pl * 128 + ss * 16;
      byt ^= (pl & 7) << 4;
      uint4 vv = *reinterpret_cast<const uint4*>(reinterpret_cast<const char*>(lds) + byt);
      *reinterpret_cast<uint4*>(outT + ((size_t)img * NPIX + P0 + pl) * 64 + ss * 8) = vv;
    }
  }
}

// --------------------- fused x_big: bn(1x1(x)) + mask * bn(3x3(h_f)), oc-split
__global__ __launch_bounds__(BLK, 2) void conv_xbig_bf(
    const __bf16* __restrict__ hfT, const __bf16* __restrict__ xT,
    const __bf16* __restrict__ wp3, const __bf16* __restrict__ wp1,
    const float* __restrict__ g2v, const float* __restrict__ b2v,
    const float* __restrict__ gdv, const float* __restrict__ bdv,
    const float* __restrict__ maskv, float* __restrict__ out) {
  constexpr int W_IMG = 56, ROWS = 6, COLS = 58, NPIX = 3136, NT = 25;
  __shared__ __bf16 lds[ROWS * COLS * 40];

  const int tid = threadIdx.x;
  const int lane = tid & 63, wv = tid >> 6;
  const int wm = wv >> 1, wn = wv & 1;
  const int quad = lane >> 4, li = lane & 15;

  const int F = blockIdx.x + NT * (blockIdx.y + 128 * blockIdx.z);
  constexpr int TOT = NT * 128 * 2;
  int Wk = (F & 7) * (TOT >> 3) + (F >> 3);
  const int bz = Wk & 1;
  const int u  = Wk >> 1;
  const int img  = u / NT;
  const int tile = u - img * NT;
  const int P0 = tile * 128;
  const int h0 = P0 / W_IMG;
  const float m = maskv[img];

  int basee[4]; int pstore[4]; bool pok[4];
#pragma unroll
  for (int nt = 0; nt < 4; ++nt) {
    int p = P0 + wn * 64 + nt * 16 + li;
    bool ok = p < NPIX;
    int p2 = ok ? p : (NPIX - 1);
    int h = p2 / W_IMG, w = p2 - h * W_IMG;
    basee[nt] = ((h - h0) * COLS + w) * 40 + quad * 8;
    pstore[nt] = p2; pok[nt] = ok;
  }

  f32x4 acc3[2][4], acc1[2][4];
#pragma unroll
  for (int mt = 0; mt < 2; ++mt)
#pragma unroll
    for (int nt = 0; nt < 4; ++nt) {
      acc3[mt][nt] = (f32x4){0.f, 0.f, 0.f, 0.f};
      acc1[mt][nt] = (f32x4){0.f, 0.f, 0.f, 0.f};
    }

  const bf16x8* wp3v = reinterpret_cast<const bf16x8*>(wp3);
  const bf16x8* wp1v = reinterpret_cast<const bf16x8*>(wp1);

  bf16x8 wr[18];
  Stage<56, 6> st;
  st.load(hfT, 128, 0, img, h0);

  // phase 1: 3x3 over h_f, CIN=128
  for (int q = 0; q < 4; ++q) {
    __syncthreads();
    st.store(lds);
    __syncthreads();
#pragma unroll
    for (int t = 0; t < 9; ++t)
#pragma unroll
      for (int mt = 0; mt < 2; ++mt)
        wr[t * 2 + mt] = wp3v[(size_t)((q * 9 + t) * 8 + bz * 4 + wm * 2 + mt) * 64 + lane];
    __builtin_amdgcn_sched_barrier(0);
    if (q < 3) st.load(hfT, 128, (q + 1) * 32, img, h0);
    else       st.load(xT, 64, 0, img, h0);
#pragma unroll
    for (int t = 0; t < 9; ++t) {
      const int toff = ((t / 3) * COLS + (t % 3)) * 40;
      bf16x8 xf[4];
#pragma unroll
      for (int nt = 0; nt < 4; ++nt)
        xf[nt] = *reinterpret_cast<const bf16x8*>(&lds[basee[nt] + toff]);
#pragma unroll
      for (int mt = 0; mt < 2; ++mt)
#pragma unroll
        for (int nt = 0; nt < 4; ++nt)
          acc3[mt][nt] = __builtin_amdgcn_mfma_f32_16x16x32_bf16(wr[t * 2 + mt], xf[nt], acc3[mt][nt], 0, 0, 0);
    }
  }

  // phase 2: 1x1 over x, CIN=64 (center tap)
  for (int q = 0; q < 2; ++q) {
    __syncthreads();
    st.store(lds);
    __syncthreads();
    bf16x8 w1[2];
#pragma unroll
    for (int mt = 0; mt < 2; ++mt)
      w1[mt] = wp1v[(size_t)(q * 8 + bz * 4 + wm * 2 + mt) * 64 + lane];
    __builtin_amdgcn_sched_barrier(0);
    if (q == 0) st.load(xT, 64, 32, img, h0);
    const int toff = (1 * COLS + 1) * 40;
    bf16x8 xf[4];
#pragma unroll
    for (int nt = 0; nt < 4; ++nt)
      xf[nt] = *reinterpret_cast<const bf16x8*>(&lds[basee[nt] + toff]);
#pragma unroll
    for (int mt = 0; mt < 2; ++mt)
#pragma unroll
      for (int nt = 0; nt < 4; ++nt)
        acc1[mt][nt] = __builtin_amdgcn_mfma_f32_16x16x32_bf16(w1[mt], xf[nt], acc1[mt][nt], 0, 0, 0);
  }

#pragma unroll
  for (int mt = 0; mt < 2; ++mt) {
#pragma unroll
    for (int r = 0; r < 4; ++r) {
      int oc = bz * 64 + wm * 32 + mt * 16 + quad * 4 + r;
      float g2 = g2v[oc], b2 = b2v[oc], gd = gdv[oc], bd = bdv[oc];
#pragma unroll
      for (int nt = 0; nt < 4; ++nt) {
        if (!pok[nt]) continue;
        size_t idx = ((size_t)img * 128 + oc) * NPIX + pstore[nt];
        float v = (acc1[mt][nt][r] * gd + bd) + m * (acc3[mt][nt][r] * g2 + b2);
        out[idx] = v;
      }
    }
  }
}

// --------------------------------------------- base_transform 1x1 conv + bn
__global__ __launch_bounds__(BLK) void conv1x1_bt_k(
    const float* __restrict__ xl, const float* __restrict__ w,
    const float* __restrict__ g, const float* __restrict__ bt, float* __restrict__ out) {
  const int b = blockIdx.z;
  const int oc0 = blockIdx.y * 8;
  const float* __restrict__ xp = xl + (size_t)b * 64 * 784;
  float gr[8], br[8];
#pragma unroll
  for (int j = 0; j < 8; ++j) {
    gr[j] = g[oc0 + j];
    br[j] = bt[oc0 + j];
  }
  for (int p = (int)threadIdx.x; p < 784; p += BLK) {
    float acc[8];
#pragma unroll
    for (int j = 0; j < 8; ++j) acc[j] = 0.f;
    for (int c = 0; c < 64; ++c) {
      float xv = xp[c * 784 + p];
#pragma unroll
      for (int j = 0; j < 8; ++j) acc[j] += xv * w[(oc0 + j) * 64 + c];
    }
#pragma unroll
    for (int j = 0; j < 8; ++j)
      out[(size_t)(b * 128 + oc0 + j) * 784 + p] = acc[j] * gr[j] + br[j];
  }
}

// ------------------------------------- GAP of (x_big + upsampled x_little)
__global__ __launch_bounds__(BLK) void gap2_k(const float* __restrict__ xbig,
                                              const float* __restrict__ xlbt,
                                              float* __restrict__ ysum) {
  __shared__ float sm1[4], sm2[4];
  const int bo = blockIdx.x;
  const float4* p4 = reinterpret_cast<const float4*>(xbig + (size_t)bo * 3136);
  float s1 = 0.f;
  for (int i = threadIdx.x; i < 784; i += BLK) {
    float4 v = p4[i];
    s1 += (v.x + v.y) + (v.z + v.w);
  }
  const float4* q4 = reinterpret_cast<const float4*>(xlbt + (size_t)bo * 784);
  float s2 = 0.f;
  for (int i = threadIdx.x; i < 196; i += BLK) {
    float4 v = q4[i];
    s2 += (v.x + v.y) + (v.z + v.w);
  }
  s1 = block_reduce_sum(s1, sm1);
  s2 = block_reduce_sum(s2, sm2);
  if (threadIdx.x == 0) ysum[bo] = s1 * (1.f / 3136.f) + s2 * (1.f / 784.f);
}

// ----------------------------------------------------- SE attention weights
__global__ void att_k(const float* __restrict__ ysum, const float* __restrict__ w1,
                      const float* __restrict__ w2, float* __restrict__ att) {
  int b = blockIdx.x;
  int t = threadIdx.x;
  __shared__ float hid[8];
  __shared__ float ybuf[128];
  ybuf[t] = ysum[b * 128 + t];
  __syncthreads();
  if (t < 8) {
    float s = 0.f;
    for (int c = 0; c < 128; ++c) s += ybuf[c] * w1[t * 128 + c];
    hid[t] = fmaxf(s, 0.f);
  }
  __syncthreads();
  float s = 0.f;
#pragma unroll
  for (int j = 0; j < 8; ++j) s += hid[j] * w2[t * 8 + j];
  att[b * 128 + t] = 1.f / (1.f + expf(-s));
}

// ------------------------------- SE combine: relu(a*xl_up + (1-a)*x_big)
__global__ __launch_bounds__(BLK) void se_k(const float* __restrict__ xlbt,
                                            const float* __restrict__ att,
                                            float* __restrict__ out) {
  int idx = blockIdx.x * BLK + threadIdx.x;
  int p = idx % 3136;
  int bo = idx / 3136;
  int h = p / 56, w = p % 56;
  float a = att[bo];
  float xl = xlbt[(size_t)bo * 784 + (h >> 1) * 28 + (w >> 1)];
  float xb = out[idx];
  out[idx] = fmaxf(a * xl + (1.f - a) * xb, 0.f);
}

// ---------------------------------------------------------------- launcher
extern "C" void kernel_launch(void* const* d_in, const int* in_sizes, int n_in,
                              void* d_out, int out_size, void* d_ws, size_t ws_size,
                              hipStream_t stream) {
  const float* x      = (const float*)d_in[0];
  const float* gumbel = (const float*)d_in[1];
  const float* nav_w  = (const float*)d_in[2];
  const float* nbg    = (const float*)d_in[3];
  const float* nbb    = (const float*)d_in[4];
  const float* gsw    = (const float*)d_in[5];
  const float* gsb    = (const float*)d_in[6];
  const float* ba_w1  = (const float*)d_in[7];
  const float* ba_g1  = (const float*)d_in[8];
  const float* ba_b1  = (const float*)d_in[9];
  const float* ba_w2  = (const float*)d_in[10];
  const float* ba_g2  = (const float*)d_in[11];
  const float* ba_b2  = (const float*)d_in[12];
  const float* bf_wd  = (const float*)d_in[13];
  const float* bf_gd  = (const float*)d_in[14];
  const float* bf_bd  = (const float*)d_in[15];
  const float* bf_w1  = (const float*)d_in[16];
  const float* bf_g1  = (const float*)d_in[17];
  const float* bf_b1  = (const float*)d_in[18];
  const float* bf_w2  = (const float*)d_in[19];
  const float* bf_g2  = (const float*)d_in[20];
  const float* bf_b2  = (const float*)d_in[21];
  const float* bt_w   = (const float*)d_in[22];
  const float* bt_g   = (const float*)d_in[23];
  const float* bt_b   = (const float*)d_in[24];
  const float* att_w1 = (const float*)d_in[25];
  const float* att_w2 = (const float*)d_in[26];
  const float* fu_w1  = (const float*)d_in[27];
  const float* fu_g1  = (const float*)d_in[28];
  const float* fu_b1  = (const float*)d_in[29];
  const float* fu_w2  = (const float*)d_in[30];
  const float* fu_g2  = (const float*)d_in[31];
  const float* fu_b2  = (const float*)d_in[32];

  float* out = (float*)d_out;
  float* ws  = (float*)d_ws;

  const size_t N_OUT = 51380224;  // 128*128*56*56
  float* bufA = ws;
  __bf16* hfbf  = (__bf16*)bufA;
  __bf16* hfubf = (__bf16*)bufA;
  __bf16* xbf   = (__bf16*)(bufA + 25690112);
  __bf16* outbf = (__bf16*)(bufA + 25690112);
  float* xlbt = bufA + N_OUT;     // [128,128,28,28]
  float* resl = xlbt + 12845056;  // res_l -> x_little
  __bf16* habf = (__bf16*)(resl + 6422528);  // [128,784,64] bf16
  float* ygap = resl + 6422528 + 6422528;    // [128,64]
  float* mskv = ygap + 8192;      // [128]
  float* ysum = mskv + 128;       // [128,128]
  float* attb = ysum + 16384;     // [128,128]
  float* wend = attb + 16384;
  __bf16* wsW1 = (__bf16*)(wend);                 // 73728 bf16
  __bf16* wsW2 = (__bf16*)(wend + 36864);         // 147456 bf16
  __bf16* wsF1 = (__bf16*)(wend + 110592);        // 147456 bf16
  __bf16* wsF2 = (__bf16*)(wend + 184320);        // 147456 bf16
  __bf16* wsA2 = (__bf16*)(wend + 258048);        // 36864 bf16
  __bf16* wsWd = (__bf16*)(wend + 276480);        // 8192 bf16
  __bf16* wsA1 = (__bf16*)(wend + 280576);        // 36864 bf16 (ba_w1 pack)
  float* mask_out = out + ((size_t)out_size - 128);

  // weight prepack (bf16 fragment layout)
  pack3_k<<<36, BLK, 0, stream>>>(bf_w1, wsW1, 64, 8);
  pack3_k<<<72, BLK, 0, stream>>>(bf_w2, wsW2, 128, 8);
  pack3_k<<<72, BLK, 0, stream>>>(fu_w1, wsF1, 128, 8);
  pack3_k<<<72, BLK, 0, stream>>>(fu_w2, wsF2, 128, 8);
  pack3_k<<<18, BLK, 0, stream>>>(ba_w2, wsA2, 64, 4);
  pack3_k<<<18, BLK, 0, stream>>>(ba_w1, wsA1, 64, 4);
  pack1_k<<<4, BLK, 0, stream>>>(bf_wd, wsWd, 64, 8);

  // x -> bf16 [pix][64]
  txp_k<64><<<dim3(49, 128), BLK, 0, stream>>>(x, xbf, 3136);

  // navigation mask
  gap_x_k<<<8192, BLK, 0, stream>>>(x, ygap);
  mask_k<<<1, 128, 0, stream>>>(ygap, gumbel, nav_w, nbg, nbb, gsw, gsb, mskv, mask_out);

  // ample branch
  avgpool_k<<<25088, BLK, 0, stream>>>(x, resl);
  conv_ba1_mfma<<<dim3(7, 128), BLK, 0, stream>>>(xbf, wsA1, ba_g1, ba_b1, habf);
  conv3s_bf<28, 64, 2, 1, 0, 1><<<dim3(7, 128), BLK, 0, stream>>>(
      habf, wsA2, ba_g2, ba_b2, resl, resl);
  conv1x1_bt_k<<<dim3(1, 16, 128), BLK, 0, stream>>>(resl, bt_w, bt_g, bt_b, xlbt);

  // focal branch
  conv3s_bf<56, 64, 2, 0, 1, 2><<<dim3(25, 128, 2), BLK, 0, stream>>>(
      xbf, wsW1, bf_g1, bf_b1, nullptr, hfbf);
  conv_xbig_bf<<<dim3(25, 128, 2), BLK, 0, stream>>>(
      hfbf, xbf, wsW2, wsWd, bf_g2, bf_b2, bf_gd, bf_bd, mskv, out);

  // SE fusion
  gap2_k<<<16384, BLK, 0, stream>>>(out, xlbt, ysum);
  att_k<<<128, 128, 0, stream>>>(ysum, att_w1, att_w2, attb);
  se_k<<<200704, BLK, 0, stream>>>(xlbt, attb, out);

  // out -> bf16 [pix][128]  (xbf is dead now; reuse A2)
  txp_k<128><<<dim3(49, 128), BLK, 0, stream>>>(out, outbf, 3136);

  // fusion residual block
  conv3s_bf<56, 128, 2, 0, 1, 2><<<dim3(25, 128, 2), BLK, 0, stream>>>(
      outbf, wsF1, fu_g1, fu_b1, nullptr, hfubf);
  conv3s_bf<56, 128, 2, 2, 0, 2><<<dim3(25, 128, 2), BLK, 0, stream>>>(
      hfubf, wsF2, fu_g2, fu_b2, out, out);
}

// Round 5
// 1794.804 us; speedup vs baseline: 1.9219x; 1.0362x over previous
//
#include <hip/hip_runtime.h>
#include <cstdint>
#include <cstddef>

#define BLK 256

typedef __bf16 bf16x8 __attribute__((ext_vector_type(8)));
typedef float  f32x4  __attribute__((ext_vector_type(4)));

// ---------------------------------------------------------------- reductions
__device__ __forceinline__ float block_reduce_sum(float v, float* sm) {
#pragma unroll
  for (int off = 32; off > 0; off >>= 1) v += __shfl_down(v, off, 64);
  const int lane = threadIdx.x & 63;
  const int wid  = threadIdx.x >> 6;
  if (lane == 0) sm[wid] = v;
  __syncthreads();
  v = sm[0] + sm[1] + sm[2] + sm[3];
  __syncthreads();
  return v;
}

// ------------------------------------------------------- global average pool
__global__ __launch_bounds__(BLK) void gap_x_k(const float* __restrict__ x,
                                               float* __restrict__ y) {
  __shared__ float sm[4];
  const float4* p4 = reinterpret_cast<const float4*>(x + (size_t)blockIdx.x * 3136);
  float s = 0.f;
  for (int i = threadIdx.x; i < 784; i += BLK) {
    float4 v = p4[i];
    s += (v.x + v.y) + (v.z + v.w);
  }
  s = block_reduce_sum(s, sm);
  if (threadIdx.x == 0) y[blockIdx.x] = s * (1.f / 3136.f);
}

// ------------------------------------------------------------ gumbel mask
__global__ void mask_k(const float* __restrict__ y, const float* __restrict__ gumbel,
                       const float* __restrict__ nav_w, const float* __restrict__ nbg,
                       const float* __restrict__ nbb, const float* __restrict__ gsw,
                       const float* __restrict__ gsb, float* __restrict__ maskv,
                       float* __restrict__ mask_out) {
  int b = threadIdx.x;
  float d0 = 0.f, d1 = 0.f;
  for (int c = 0; c < 64; ++c) {
    float yv = y[b * 64 + c];
    d0 += yv * nav_w[c];
    d1 += yv * nav_w[64 + c];
  }
  float g0 = fmaxf(d0 * nbg[0] + nbb[0], 0.f);
  float g1 = fmaxf(d1 * nbg[1] + nbb[1], 0.f);
  int vid = b >> 3, s = b & 7;
  float l0 = gsw[s * 4 + 0] * g0 + gsw[s * 4 + 1] * g1 + gsb[s * 2 + 0] + gumbel[(vid * 8 + s) * 2 + 0];
  float l1 = gsw[s * 4 + 2] * g0 + gsw[s * 4 + 3] * g1 + gsb[s * 2 + 1] + gumbel[(vid * 8 + s) * 2 + 1];
  float m = (l1 > l0) ? 1.f : 0.f;
  maskv[b] = m;
  mask_out[b] = m;
}

// ------------------------------------------------ avgpool 3x3 s2 p1
__global__ __launch_bounds__(BLK) void avgpool_k(const float* __restrict__ x,
                                                 float* __restrict__ out) {
  int idx = blockIdx.x * BLK + threadIdx.x;
  int p = idx % 784;
  int bc = idx / 784;
  int h = p / 28, w = p % 28;
  const float* xp = x + (size_t)bc * 3136;
  int h0 = 2 * h - 1, w0 = 2 * w - 1;
  float s = 0.f;
#pragma unroll
  for (int i = 0; i < 3; ++i) {
    int hh = h0 + i;
    if (hh < 0 || hh >= 56) continue;
#pragma unroll
    for (int j = 0; j < 3; ++j) {
      int ww = w0 + j;
      if (ww < 0 || ww >= 56) continue;
      s += xp[hh * 56 + ww];
    }
  }
  out[idx] = s * (1.f / 9.f);
}

// ---------------------------------------------- fp32->bf16 [ch][pix] -> [pix][ch]
template <int C>
__global__ __launch_bounds__(BLK) void txp_k(const float* __restrict__ src,
                                             __bf16* __restrict__ dst, int NP) {
  __shared__ float t[C * 65];
  const int b = blockIdx.y;
  const int p0 = blockIdx.x * 64;
  for (int i = threadIdx.x; i < C * 64; i += BLK) {
    int c = i >> 6, p = i & 63;
    float v = 0.f;
    if (p0 + p < NP) v = src[((size_t)b * C + c) * NP + p0 + p];
    t[c * 65 + p] = v;
  }
  __syncthreads();
  constexpr int CQ = C / 8;
  for (int i = threadIdx.x; i < 64 * CQ; i += BLK) {
    int cq = i % CQ, pix = i / CQ;
    if (p0 + pix < NP) {
      __bf16 o[8];
#pragma unroll
      for (int j = 0; j < 8; ++j) o[j] = (__bf16)t[(cq * 8 + j) * 65 + pix];
      *reinterpret_cast<uint4*>(dst + ((size_t)b * NP + p0 + pix) * C + cq * 8) =
          *reinterpret_cast<uint4*>(o);
    }
  }
}

// ------------- fused SE + transpose: out = relu(a*xl_up + (1-a)*out) -> fp32 + bf16T
__global__ __launch_bounds__(BLK) void txpse_k(float* __restrict__ outio,
                                               const float* __restrict__ xlbt,
                                               const float* __restrict__ att,
                                               __bf16* __restrict__ dst) {
  __shared__ float t[128 * 65];
  const int b = blockIdx.y;
  const int p0 = blockIdx.x * 64;   // 49*64 == 3136 exactly
  for (int i = threadIdx.x; i < 128 * 64; i += BLK) {
    int c = i >> 6, p = i & 63;
    int pg = p0 + p;
    size_t idx = ((size_t)b * 128 + c) * 3136 + pg;
    float v = outio[idx];
    int h = pg / 56, w = pg - h * 56;
    float xl = xlbt[((size_t)b * 128 + c) * 784 + (h >> 1) * 28 + (w >> 1)];
    float a = att[b * 128 + c];
    float r = fmaxf(a * xl + (1.f - a) * v, 0.f);
    outio[idx] = r;
    t[c * 65 + p] = r;
  }
  __syncthreads();
  for (int i = threadIdx.x; i < 64 * 16; i += BLK) {
    int cq = i % 16, pix = i / 16;
    __bf16 o[8];
#pragma unroll
    for (int j = 0; j < 8; ++j) o[j] = (__bf16)t[(cq * 8 + j) * 65 + pix];
    *reinterpret_cast<uint4*>(dst + ((size_t)b * 3136 + p0 + pix) * 128 + cq * 8) =
        *reinterpret_cast<uint4*>(o);
  }
}

// ------------------------------------------------------- weight prepack (3x3)
__global__ void pack3_k(const float* __restrict__ w, __bf16* __restrict__ dst,
                        int CIN, int MT) {
  int total = (CIN / 32) * 9 * MT * 64;
  int idx = blockIdx.x * BLK + threadIdx.x;
  if (idx >= total) return;
  int lane = idx & 63;
  int g = idx >> 6;
  int mt = g % MT; g /= MT;
  int t = g % 9;  int q = g / 9;
  int oc = mt * 16 + (lane & 15);
  int quad = lane >> 4;
#pragma unroll
  for (int j = 0; j < 8; ++j) {
    int c = q * 32 + quad * 8 + j;
    dst[(size_t)idx * 8 + j] = (__bf16)w[((size_t)oc * CIN + c) * 9 + t];
  }
}

// 1x1 variant
__global__ void pack1_k(const float* __restrict__ w, __bf16* __restrict__ dst,
                        int CIN, int MT) {
  int total = (CIN / 32) * MT * 64;
  int idx = blockIdx.x * BLK + threadIdx.x;
  if (idx >= total) return;
  int lane = idx & 63;
  int g = idx >> 6;
  int mt = g % MT;
  int q = g / MT;
  int oc = mt * 16 + (lane & 15);
  int quad = lane >> 4;
#pragma unroll
  for (int j = 0; j < 8; ++j) {
    int c = q * 32 + quad * 8 + j;
    dst[(size_t)idx * 8 + j] = (__bf16)w[(size_t)oc * CIN + c];
  }
}

// ------------------------------------------------ staging: bf16 [pix][ch] -> regs -> LDS
// LDS tile: [pix][32ch] bf16, pixel stride 40 (pad 8).  One 16B slot = 8 channels.
template <int W_IMG, int ROWS>
struct Stage {
  static constexpr int COLS  = W_IMG + 2;
  static constexpr int NSLOT = ROWS * COLS * 4;
  static constexpr int NIT   = (NSLOT + BLK - 1) / BLK;
  uint4 R[NIT];

  __device__ __forceinline__ void load(const __bf16* __restrict__ inT, int CIN, int c0,
                                       int img, int h0) {
    constexpr int NPIX = W_IMG * W_IMG;
#pragma unroll
    for (int it = 0; it < NIT; ++it) {
      int s = threadIdx.x + it * BLK;
      uint4 v{0u, 0u, 0u, 0u};
      if (s < NSLOT) {
        int pix = s >> 2, q = s & 3;
        int r = pix / COLS, cc = pix - r * COLS;
        int gh = h0 - 1 + r, gw = cc - 1;
        if (gh >= 0 && gh < W_IMG && gw >= 0 && gw < W_IMG)
          v = *reinterpret_cast<const uint4*>(
              inT + ((size_t)img * NPIX + gh * W_IMG + gw) * CIN + c0 + q * 8);
      }
      R[it] = v;
    }
  }

  __device__ __forceinline__ void store(__bf16* lds) {
#pragma unroll
    for (int it = 0; it < NIT; ++it) {
      int s = threadIdx.x + it * BLK;
      if (s < NSLOT) {
        int pix = s >> 2, q = s & 3;
        *reinterpret_cast<uint4*>(lds + pix * 40 + q * 8) = R[it];
      }
    }
  }
};

// --------------------------------------------------------- MFMA 3x3 conv (oc-split)
// block: 128 linear pixels x (MTW*2*16) ocs, gridDim.z oc-split.
// 4 waves in 2x2 (wm, wn).  Per-chunk weights hoisted to regs BEFORE staging
// loads are issued (vmcnt FIFO: weight waits leave staging in flight).
// MODE 0: relu(bn)  MODE 1: bn+res  MODE 2: relu(bn+res)
// OUTBF 1: write bf16 [pix][COUT_G] (MODE 0 semantics) via LDS transpose
template <int W_IMG, int CIN, int MTW, int MODE, int OUTBF, int NSPLIT>
__global__ __launch_bounds__(BLK, 3) void conv3s_bf(
    const __bf16* __restrict__ inT, const __bf16* __restrict__ wp,
    const float* __restrict__ gamma, const float* __restrict__ beta,
    const float* __restrict__ res, void* __restrict__ outv) {
  constexpr int ROWS = 128 / W_IMG + 4;
  constexpr int COLS = W_IMG + 2;
  constexpr int NPIX = W_IMG * W_IMG;
  constexpr int NCH  = CIN / 32;
  constexpr int MT_TOT = MTW * 2;         // per block
  constexpr int COUT_B = MT_TOT * 16;     // per block
  constexpr int COUT_G = COUT_B * NSPLIT; // global
  constexpr int MT_TOTG = COUT_G / 16;
  constexpr int NT = (NPIX + 127) / 128;
  constexpr int TILE_E = ROWS * COLS * 40;
  constexpr int LDSE = (OUTBF && 128 * COUT_B > TILE_E) ? 128 * COUT_B : TILE_E;
  __shared__ __bf16 lds[LDSE];

  const int tid = threadIdx.x;
  const int lane = tid & 63, wv = tid >> 6;
  const int wm = wv >> 1, wn = wv & 1;
  const int quad = lane >> 4, li = lane & 15;

  // XCD-aware swizzle: same-XCD gets contiguous (img,tile) range; oc-halves paired.
  const int F = blockIdx.x + NT * (blockIdx.y + 128 * blockIdx.z);
  constexpr int TOT = NT * 128 * NSPLIT;  // divisible by 8
  int Wk = (F & 7) * (TOT >> 3) + (F >> 3);
  int bz, u;
  if constexpr (NSPLIT == 2) { bz = Wk & 1; u = Wk >> 1; }
  else                       { bz = 0;      u = Wk;      }
  const int img  = u / NT;
  const int tile = u - img * NT;
  const int P0 = tile * 128;
  const int h0 = P0 / W_IMG;
  const int mtg0 = bz * MT_TOT + wm * MTW;

  int basee[4]; int pstore[4]; bool pok[4];
#pragma unroll
  for (int nt = 0; nt < 4; ++nt) {
    int p = P0 + wn * 64 + nt * 16 + li;
    bool ok = p < NPIX;
    int p2 = ok ? p : (NPIX - 1);
    int h = p2 / W_IMG, w = p2 - h * W_IMG;
    basee[nt] = ((h - h0) * COLS + w) * 40 + quad * 8;
    pstore[nt] = p2; pok[nt] = ok;
  }

  f32x4 acc[MTW][4];
#pragma unroll
  for (int mt = 0; mt < MTW; ++mt)
#pragma unroll
    for (int nt = 0; nt < 4; ++nt) acc[mt][nt] = (f32x4){0.f, 0.f, 0.f, 0.f};

  const bf16x8* wp8 = reinterpret_cast<const bf16x8*>(wp);

  bf16x8 wr[9 * MTW];
  Stage<W_IMG, ROWS> st;
  st.load(inT, CIN, 0, img, h0);
  for (int q = 0; q < NCH; ++q) {
    __syncthreads();
    st.store(lds);
    __syncthreads();
#pragma unroll
    for (int t = 0; t < 9; ++t)
#pragma unroll
      for (int mt = 0; mt < MTW; ++mt)
        wr[t * MTW + mt] = wp8[(size_t)((q * 9 + t) * MT_TOTG + mtg0 + mt) * 64 + lane];
    __builtin_amdgcn_sched_barrier(0);   // weights issue before next staging (vmcnt FIFO)
    if (q + 1 < NCH) st.load(inT, CIN, (q + 1) * 32, img, h0);
#pragma unroll
    for (int t = 0; t < 9; ++t) {
      const int toff = ((t / 3) * COLS + (t % 3)) * 40;
      bf16x8 xf[4];
#pragma unroll
      for (int nt = 0; nt < 4; ++nt)
        xf[nt] = *reinterpret_cast<const bf16x8*>(&lds[basee[nt] + toff]);
#pragma unroll
      for (int mt = 0; mt < MTW; ++mt)
#pragma unroll
        for (int nt = 0; nt < 4; ++nt)
          acc[mt][nt] = __builtin_amdgcn_mfma_f32_16x16x32_bf16(wr[t * MTW + mt], xf[nt], acc[mt][nt], 0, 0, 0);
    }
  }

  if constexpr (!OUTBF) {
    float* out = (float*)outv;
#pragma unroll
    for (int mt = 0; mt < MTW; ++mt) {
#pragma unroll
      for (int r = 0; r < 4; ++r) {
        int oc = bz * COUT_B + wm * MTW * 16 + mt * 16 + quad * 4 + r;
        float g = gamma[oc], bb = beta[oc];
#pragma unroll
        for (int nt = 0; nt < 4; ++nt) {
          if (!pok[nt]) continue;
          size_t idx = ((size_t)img * COUT_G + oc) * NPIX + pstore[nt];
          float v = acc[mt][nt][r] * g + bb;
          if constexpr (MODE == 1 || MODE == 2) v += res[idx];
          if constexpr (MODE == 0 || MODE == 2) v = fmaxf(v, 0.f);
          out[idx] = v;
        }
      }
    }
  } else {
    // bf16 [pix][COUT_G] output via swizzled LDS transpose -> coalesced 16B stores
    __bf16* outT = (__bf16*)outv;
    __syncthreads();  // tile reads done; reuse LDS
#pragma unroll
    for (int mt = 0; mt < MTW; ++mt) {
      int ocl = wm * MTW * 16 + mt * 16 + quad * 4;   // local 0..COUT_B-1
      int ocg = bz * COUT_B + ocl;
      float g0 = gamma[ocg + 0], b0 = beta[ocg + 0];
      float g1 = gamma[ocg + 1], b1 = beta[ocg + 1];
      float g2 = gamma[ocg + 2], b2 = beta[ocg + 2];
      float g3 = gamma[ocg + 3], b3 = beta[ocg + 3];
#pragma unroll
      for (int nt = 0; nt < 4; ++nt) {
        if (!pok[nt]) continue;
        int pl = wn * 64 + nt * 16 + li;   // local pixel 0..127
        __bf16 o[4];
        o[0] = (__bf16)fmaxf(acc[mt][nt][0] * g0 + b0, 0.f);
        o[1] = (__bf16)fmaxf(acc[mt][nt][1] * g1 + b1, 0.f);
        o[2] = (__bf16)fmaxf(acc[mt][nt][2] * g2 + b2, 0.f);
        o[3] = (__bf16)fmaxf(acc[mt][nt][3] * g3 + b3, 0.f);
        int byt = pl * (COUT_B * 2) + ocl * 2;
        byt ^= (pl & 7) << 4;              // bank swizzle (row stride 128B)
        *reinterpret_cast<uint2*>(reinterpret_cast<char*>(lds) + byt) =
            *reinterpret_cast<uint2*>(o);
      }
    }
    __syncthreads();
    constexpr int SLOTS_ROW = COUT_B / 8;       // 8
    constexpr int ROWS_PASS = BLK / SLOTS_ROW;  // 32
#pragma unroll
    for (int pass = 0; pass < 128 / ROWS_PASS; ++pass) {
      int pl = pass * ROWS_PASS + (tid / SLOTS_ROW);
      int ss = tid % SLOTS_ROW;
      if (P0 + pl < NPIX) {
        int byt = pl * (COUT_B * 2) + ss * 16;
        byt ^= (pl & 7) << 4;
        uint4 vv = *reinterpret_cast<const uint4*>(reinterpret_cast<const char*>(lds) + byt);
        *reinterpret_cast<uint4*>(outT + ((size_t)img * NPIX + P0 + pl) * COUT_G + bz * COUT_B + ss * 8) = vv;
      }
    }
  }
}

// ----------------- stride-2 3x3 MFMA conv: 56x56x64 -> 28x28x64, relu(bn), bf16 out
// block: 128 linear output pixels x 64 ocs. 4 waves 2x2.  Weight hoist per chunk.
__global__ __launch_bounds__(BLK, 2) void conv_ba1_mfma(
    const __bf16* __restrict__ xT, const __bf16* __restrict__ wp,
    const float* __restrict__ gamma, const float* __restrict__ beta,
    __bf16* __restrict__ outT) {
  constexpr int WOUT = 28, NPIX = 784;
  constexpr int ROWS = 13, COLS = 58;
  constexpr int TILE_E = ROWS * COLS * 40;
  __shared__ __bf16 lds[TILE_E];

  const int tid = threadIdx.x;
  const int lane = tid & 63, wv = tid >> 6;
  const int wm = wv >> 1, wn = wv & 1;
  const int quad = lane >> 4, li = lane & 15;
  const int img = blockIdx.y;
  const int P0 = blockIdx.x * 128;
  const int h0 = P0 / WOUT;

  int basee[4]; bool pok[4];
#pragma unroll
  for (int nt = 0; nt < 4; ++nt) {
    int p = P0 + wn * 64 + nt * 16 + li;
    bool ok = p < NPIX;
    int p2 = ok ? p : (NPIX - 1);
    int h = p2 / WOUT, w = p2 - h * WOUT;
    basee[nt] = (2 * (h - h0) * COLS + 2 * w) * 40 + quad * 8;
    pok[nt] = ok;
  }

  f32x4 acc[2][4];
#pragma unroll
  for (int mt = 0; mt < 2; ++mt)
#pragma unroll
    for (int nt = 0; nt < 4; ++nt) acc[mt][nt] = (f32x4){0.f, 0.f, 0.f, 0.f};

  const bf16x8* wp8 = reinterpret_cast<const bf16x8*>(wp);

  bf16x8 wr[18];
  Stage<56, 13> st;
  st.load(xT, 64, 0, img, 2 * h0);
  for (int q = 0; q < 2; ++q) {
    __syncthreads();
    st.store(lds);
    __syncthreads();
#pragma unroll
    for (int t = 0; t < 9; ++t)
#pragma unroll
      for (int mt = 0; mt < 2; ++mt)
        wr[t * 2 + mt] = wp8[(size_t)((q * 9 + t) * 4 + wm * 2 + mt) * 64 + lane];
    __builtin_amdgcn_sched_barrier(0);
    if (q == 0) st.load(xT, 64, 32, img, 2 * h0);
#pragma unroll
    for (int t = 0; t < 9; ++t) {
      const int toff = ((t / 3) * COLS + (t % 3)) * 40;
      bf16x8 xf[4];
#pragma unroll
      for (int nt = 0; nt < 4; ++nt)
        xf[nt] = *reinterpret_cast<const bf16x8*>(&lds[basee[nt] + toff]);
#pragma unroll
      for (int mt = 0; mt < 2; ++mt)
#pragma unroll
        for (int nt = 0; nt < 4; ++nt)
          acc[mt][nt] = __builtin_amdgcn_mfma_f32_16x16x32_bf16(wr[t * 2 + mt], xf[nt], acc[mt][nt], 0, 0, 0);
    }
  }

  // epilogue: relu(bn) -> bf16 [pix][64] via swizzled LDS transpose
  __syncthreads();
#pragma unroll
  for (int mt = 0; mt < 2; ++mt) {
    int ocb = wm * 32 + mt * 16 + quad * 4;
    float g0 = gamma[ocb + 0], b0 = beta[ocb + 0];
    float g1 = gamma[ocb + 1], b1 = beta[ocb + 1];
    float g2 = gamma[ocb + 2], b2 = beta[ocb + 2];
    float g3 = gamma[ocb + 3], b3 = beta[ocb + 3];
#pragma unroll
    for (int nt = 0; nt < 4; ++nt) {
      if (!pok[nt]) continue;
      int pl = wn * 64 + nt * 16 + li;
      __bf16 o[4];
      o[0] = (__bf16)fmaxf(acc[mt][nt][0] * g0 + b0, 0.f);
      o[1] = (__bf16)fmaxf(acc[mt][nt][1] * g1 + b1, 0.f);
      o[2] = (__bf16)fmaxf(acc[mt][nt][2] * g2 + b2, 0.f);
      o[3] = (__bf16)fmaxf(acc[mt][nt][3] * g3 + b3, 0.f);
      int byt = pl * 128 + ocb * 2;
      byt ^= (pl & 7) << 4;
      *reinterpret_cast<uint2*>(reinterpret_cast<char*>(lds) + byt) =
          *reinterpret_cast<uint2*>(o);
    }
  }
  __syncthreads();
#pragma unroll
  for (int pass = 0; pass < 4; ++pass) {
    int pl = pass * 32 + (tid >> 3);
    int ss = tid & 7;
    if (P0 + pl < NPIX) {
      int byt = pl * 128 + ss * 16;
      byt ^= (pl & 7) << 4;
      uint4 vv = *reinterpret_cast<const uint4*>(reinterpret_cast<const char*>(lds) + byt);
      *reinterpret_cast<uint4*>(outT + ((size_t)img * NPIX + P0 + pl) * 64 + ss * 8) = vv;
    }
  }
}

// --------------------- fused x_big: bn(1x1(x)) + mask * bn(3x3(h_f)), oc-split
__global__ __launch_bounds__(BLK, 3) void conv_xbig_bf(
    const __bf16* __restrict__ hfT, const __bf16* __restrict__ xT,
    const __bf16* __restrict__ wp3, const __bf16* __restrict__ wp1,
    const float* __restrict__ g2v, const float* __restrict__ b2v,
    const float* __restrict__ gdv, const float* __restrict__ bdv,
    const float* __restrict__ maskv, float* __restrict__ out) {
  constexpr int W_IMG = 56, ROWS = 6, COLS = 58, NPIX = 3136, NT = 25;
  __shared__ __bf16 lds[ROWS * COLS * 40];

  const int tid = threadIdx.x;
  const int lane = tid & 63, wv = tid >> 6;
  const int wm = wv >> 1, wn = wv & 1;
  const int quad = lane >> 4, li = lane & 15;

  const int F = blockIdx.x + NT * (blockIdx.y + 128 * blockIdx.z);
  constexpr int TOT = NT * 128 * 2;
  int Wk = (F & 7) * (TOT >> 3) + (F >> 3);
  const int bz = Wk & 1;
  const int u  = Wk >> 1;
  const int img  = u / NT;
  const int tile = u - img * NT;
  const int P0 = tile * 128;
  const int h0 = P0 / W_IMG;
  const float m = maskv[img];

  int basee[4]; int pstore[4]; bool pok[4];
#pragma unroll
  for (int nt = 0; nt < 4; ++nt) {
    int p = P0 + wn * 64 + nt * 16 + li;
    bool ok = p < NPIX;
    int p2 = ok ? p : (NPIX - 1);
    int h = p2 / W_IMG, w = p2 - h * W_IMG;
    basee[nt] = ((h - h0) * COLS + w) * 40 + quad * 8;
    pstore[nt] = p2; pok[nt] = ok;
  }

  f32x4 acc3[2][4], acc1[2][4];
#pragma unroll
  for (int mt = 0; mt < 2; ++mt)
#pragma unroll
    for (int nt = 0; nt < 4; ++nt) {
      acc3[mt][nt] = (f32x4){0.f, 0.f, 0.f, 0.f};
      acc1[mt][nt] = (f32x4){0.f, 0.f, 0.f, 0.f};
    }

  const bf16x8* wp3v = reinterpret_cast<const bf16x8*>(wp3);
  const bf16x8* wp1v = reinterpret_cast<const bf16x8*>(wp1);

  bf16x8 wr[18];
  Stage<56, 6> st;
  st.load(hfT, 128, 0, img, h0);

  // phase 1: 3x3 over h_f, CIN=128
  for (int q = 0; q < 4; ++q) {
    __syncthreads();
    st.store(lds);
    __syncthreads();
#pragma unroll
    for (int t = 0; t < 9; ++t)
#pragma unroll
      for (int mt = 0; mt < 2; ++mt)
        wr[t * 2 + mt] = wp3v[(size_t)((q * 9 + t) * 8 + bz * 4 + wm * 2 + mt) * 64 + lane];
    __builtin_amdgcn_sched_barrier(0);
    if (q < 3) st.load(hfT, 128, (q + 1) * 32, img, h0);
    else       st.load(xT, 64, 0, img, h0);
#pragma unroll
    for (int t = 0; t < 9; ++t) {
      const int toff = ((t / 3) * COLS + (t % 3)) * 40;
      bf16x8 xf[4];
#pragma unroll
      for (int nt = 0; nt < 4; ++nt)
        xf[nt] = *reinterpret_cast<const bf16x8*>(&lds[basee[nt] + toff]);
#pragma unroll
      for (int mt = 0; mt < 2; ++mt)
#pragma unroll
        for (int nt = 0; nt < 4; ++nt)
          acc3[mt][nt] = __builtin_amdgcn_mfma_f32_16x16x32_bf16(wr[t * 2 + mt], xf[nt], acc3[mt][nt], 0, 0, 0);
    }
  }

  // phase 2: 1x1 over x, CIN=64 (center tap)
  for (int q = 0; q < 2; ++q) {
    __syncthreads();
    st.store(lds);
    __syncthreads();
    bf16x8 w1[2];
#pragma unroll
    for (int mt = 0; mt < 2; ++mt)
      w1[mt] = wp1v[(size_t)(q * 8 + bz * 4 + wm * 2 + mt) * 64 + lane];
    __builtin_amdgcn_sched_barrier(0);
    if (q == 0) st.load(xT, 64, 32, img, h0);
    const int toff = (1 * COLS + 1) * 40;
    bf16x8 xf[4];
#pragma unroll
    for (int nt = 0; nt < 4; ++nt)
      xf[nt] = *reinterpret_cast<const bf16x8*>(&lds[basee[nt] + toff]);
#pragma unroll
    for (int mt = 0; mt < 2; ++mt)
#pragma unroll
      for (int nt = 0; nt < 4; ++nt)
        acc1[mt][nt] = __builtin_amdgcn_mfma_f32_16x16x32_bf16(w1[mt], xf[nt], acc1[mt][nt], 0, 0, 0);
  }

#pragma unroll
  for (int mt = 0; mt < 2; ++mt) {
#pragma unroll
    for (int r = 0; r < 4; ++r) {
      int oc = bz * 64 + wm * 32 + mt * 16 + quad * 4 + r;
      float g2 = g2v[oc], b2 = b2v[oc], gd = gdv[oc], bd = bdv[oc];
#pragma unroll
      for (int nt = 0; nt < 4; ++nt) {
        if (!pok[nt]) continue;
        size_t idx = ((size_t)img * 128 + oc) * NPIX + pstore[nt];
        float v = (acc1[mt][nt][r] * gd + bd) + m * (acc3[mt][nt][r] * g2 + b2);
        out[idx] = v;
      }
    }
  }
}

// --------------------------------------------- base_transform 1x1 conv + bn
__global__ __launch_bounds__(BLK) void conv1x1_bt_k(
    const float* __restrict__ xl, const float* __restrict__ w,
    const float* __restrict__ g, const float* __restrict__ bt, float* __restrict__ out) {
  const int b = blockIdx.z;
  const int oc0 = blockIdx.y * 8;
  const float* __restrict__ xp = xl + (size_t)b * 64 * 784;
  float gr[8], br[8];
#pragma unroll
  for (int j = 0; j < 8; ++j) {
    gr[j] = g[oc0 + j];
    br[j] = bt[oc0 + j];
  }
  for (int p = (int)threadIdx.x; p < 784; p += BLK) {
    float acc[8];
#pragma unroll
    for (int j = 0; j < 8; ++j) acc[j] = 0.f;
    for (int c = 0; c < 64; ++c) {
      float xv = xp[c * 784 + p];
#pragma unroll
      for (int j = 0; j < 8; ++j) acc[j] += xv * w[(oc0 + j) * 64 + c];
    }
#pragma unroll
    for (int j = 0; j < 8; ++j)
      out[(size_t)(b * 128 + oc0 + j) * 784 + p] = acc[j] * gr[j] + br[j];
  }
}

// ------------------------------------- GAP of (x_big + upsampled x_little)
__global__ __launch_bounds__(BLK) void gap2_k(const float* __restrict__ xbig,
                                              const float* __restrict__ xlbt,
                                              float* __restrict__ ysum) {
  __shared__ float sm1[4], sm2[4];
  const int bo = blockIdx.x;
  const float4* p4 = reinterpret_cast<const float4*>(xbig + (size_t)bo * 3136);
  float s1 = 0.f;
  for (int i = threadIdx.x; i < 784; i += BLK) {
    float4 v = p4[i];
    s1 += (v.x + v.y) + (v.z + v.w);
  }
  const float4* q4 = reinterpret_cast<const float4*>(xlbt + (size_t)bo * 784);
  float s2 = 0.f;
  for (int i = threadIdx.x; i < 196; i += BLK) {
    float4 v = q4[i];
    s2 += (v.x + v.y) + (v.z + v.w);
  }
  s1 = block_reduce_sum(s1, sm1);
  s2 = block_reduce_sum(s2, sm2);
  if (threadIdx.x == 0) ysum[bo] = s1 * (1.f / 3136.f) + s2 * (1.f / 784.f);
}

// ----------------------------------------------------- SE attention weights
__global__ void att_k(const float* __restrict__ ysum, const float* __restrict__ w1,
                      const float* __restrict__ w2, float* __restrict__ att) {
  int b = blockIdx.x;
  int t = threadIdx.x;
  __shared__ float hid[8];
  __shared__ float ybuf[128];
  ybuf[t] = ysum[b * 128 + t];
  __syncthreads();
  if (t < 8) {
    float s = 0.f;
    for (int c = 0; c < 128; ++c) s += ybuf[c] * w1[t * 128 + c];
    hid[t] = fmaxf(s, 0.f);
  }
  __syncthreads();
  float s = 0.f;
#pragma unroll
  for (int j = 0; j < 8; ++j) s += hid[j] * w2[t * 8 + j];
  att[b * 128 + t] = 1.f / (1.f + expf(-s));
}

// ---------------------------------------------------------------- launcher
extern "C" void kernel_launch(void* const* d_in, const int* in_sizes, int n_in,
                              void* d_out, int out_size, void* d_ws, size_t ws_size,
                              hipStream_t stream) {
  const float* x      = (const float*)d_in[0];
  const float* gumbel = (const float*)d_in[1];
  const float* nav_w  = (const float*)d_in[2];
  const float* nbg    = (const float*)d_in[3];
  const float* nbb    = (const float*)d_in[4];
  const float* gsw    = (const float*)d_in[5];
  const float* gsb    = (const float*)d_in[6];
  const float* ba_w1  = (const float*)d_in[7];
  const float* ba_g1  = (const float*)d_in[8];
  const float* ba_b1  = (const float*)d_in[9];
  const float* ba_w2  = (const float*)d_in[10];
  const float* ba_g2  = (const float*)d_in[11];
  const float* ba_b2  = (const float*)d_in[12];
  const float* bf_wd  = (const float*)d_in[13];
  const float* bf_gd  = (const float*)d_in[14];
  const float* bf_bd  = (const float*)d_in[15];
  const float* bf_w1  = (const float*)d_in[16];
  const float* bf_g1  = (const float*)d_in[17];
  const float* bf_b1  = (const float*)d_in[18];
  const float* bf_w2  = (const float*)d_in[19];
  const float* bf_g2  = (const float*)d_in[20];
  const float* bf_b2  = (const float*)d_in[21];
  const float* bt_w   = (const float*)d_in[22];
  const float* bt_g   = (const float*)d_in[23];
  const float* bt_b   = (const float*)d_in[24];
  const float* att_w1 = (const float*)d_in[25];
  const float* att_w2 = (const float*)d_in[26];
  const float* fu_w1  = (const float*)d_in[27];
  const float* fu_g1  = (const float*)d_in[28];
  const float* fu_b1  = (const float*)d_in[29];
  const float* fu_w2  = (const float*)d_in[30];
  const float* fu_g2  = (const float*)d_in[31];
  const float* fu_b2  = (const float*)d_in[32];

  float* out = (float*)d_out;
  float* ws  = (float*)d_ws;

  const size_t N_OUT = 51380224;  // 128*128*56*56
  float* bufA = ws;
  __bf16* hfbf  = (__bf16*)bufA;
  __bf16* hfubf = (__bf16*)bufA;
  __bf16* xbf   = (__bf16*)(bufA + 25690112);
  __bf16* outbf = (__bf16*)(bufA + 25690112);
  float* xlbt = bufA + N_OUT;     // [128,128,28,28]
  float* resl = xlbt + 12845056;  // res_l -> x_little
  __bf16* habf = (__bf16*)(resl + 6422528);  // [128,784,64] bf16
  float* ygap = resl + 6422528 + 6422528;    // [128,64]
  float* mskv = ygap + 8192;      // [128]
  float* ysum = mskv + 128;       // [128,128]
  float* attb = ysum + 16384;     // [128,128]
  float* wend = attb + 16384;
  __bf16* wsW1 = (__bf16*)(wend);                 // 73728 bf16
  __bf16* wsW2 = (__bf16*)(wend + 36864);         // 147456 bf16
  __bf16* wsF1 = (__bf16*)(wend + 110592);        // 147456 bf16
  __bf16* wsF2 = (__bf16*)(wend + 184320);        // 147456 bf16
  __bf16* wsA2 = (__bf16*)(wend + 258048);        // 36864 bf16
  __bf16* wsWd = (__bf16*)(wend + 276480);        // 8192 bf16
  __bf16* wsA1 = (__bf16*)(wend + 280576);        // 36864 bf16 (ba_w1 pack)
  float* mask_out = out + ((size_t)out_size - 128);

  // weight prepack (bf16 fragment layout)
  pack3_k<<<36, BLK, 0, stream>>>(bf_w1, wsW1, 64, 8);
  pack3_k<<<72, BLK, 0, stream>>>(bf_w2, wsW2, 128, 8);
  pack3_k<<<72, BLK, 0, stream>>>(fu_w1, wsF1, 128, 8);
  pack3_k<<<72, BLK, 0, stream>>>(fu_w2, wsF2, 128, 8);
  pack3_k<<<18, BLK, 0, stream>>>(ba_w2, wsA2, 64, 4);
  pack3_k<<<18, BLK, 0, stream>>>(ba_w1, wsA1, 64, 4);
  pack1_k<<<4, BLK, 0, stream>>>(bf_wd, wsWd, 64, 8);

  // x -> bf16 [pix][64]
  txp_k<64><<<dim3(49, 128), BLK, 0, stream>>>(x, xbf, 3136);

  // navigation mask
  gap_x_k<<<8192, BLK, 0, stream>>>(x, ygap);
  mask_k<<<1, 128, 0, stream>>>(ygap, gumbel, nav_w, nbg, nbb, gsw, gsb, mskv, mask_out);

  // ample branch
  avgpool_k<<<25088, BLK, 0, stream>>>(x, resl);
  conv_ba1_mfma<<<dim3(7, 128), BLK, 0, stream>>>(xbf, wsA1, ba_g1, ba_b1, habf);
  conv3s_bf<28, 64, 2, 1, 0, 1><<<dim3(7, 128), BLK, 0, stream>>>(
      habf, wsA2, ba_g2, ba_b2, resl, resl);
  conv1x1_bt_k<<<dim3(1, 16, 128), BLK, 0, stream>>>(resl, bt_w, bt_g, bt_b, xlbt);

  // focal branch
  conv3s_bf<56, 64, 2, 0, 1, 2><<<dim3(25, 128, 2), BLK, 0, stream>>>(
      xbf, wsW1, bf_g1, bf_b1, nullptr, hfbf);
  conv_xbig_bf<<<dim3(25, 128, 2), BLK, 0, stream>>>(
      hfbf, xbf, wsW2, wsWd, bf_g2, bf_b2, bf_gd, bf_bd, mskv, out);

  // SE fusion
  gap2_k<<<16384, BLK, 0, stream>>>(out, xlbt, ysum);
  att_k<<<128, 128, 0, stream>>>(ysum, att_w1, att_w2, attb);
  // fused SE-combine + fp32 update + bf16 [pix][128] transpose (se_k + txp_k merged)
  txpse_k<<<dim3(49, 128), BLK, 0, stream>>>(out, xlbt, attb, outbf);

  // fusion residual block
  conv3s_bf<56, 128, 2, 0, 1, 2><<<dim3(25, 128, 2), BLK, 0, stream>>>(
      outbf, wsF1, fu_g1, fu_b1, nullptr, hfubf);
  conv3s_bf<56, 128, 2, 2, 0, 2><<<dim3(25, 128, 2), BLK, 0, stream>>>(
      hfubf, wsF2, fu_g2, fu_b2, out, out);
}